// Round 11
// baseline (263.219 us; speedup 1.0000x reference)
//
#include <hip/hip_runtime.h>
#include <math.h>

#define N_NODES 600
#define N_EDGES 9600
#define HDIM    128
#define HA      256
#define HC      256
#define NN      360000
#define BN_EPS  1e-5f
#define NTILE   361    // 19 x 19 logits tiles (32x32)

// ---- block-range layout of the mega kernel ----
#define B_PRE0   0      // 25 u-slice blocks
#define B_CSR    25
#define B_WF0    26     // 16 Wf blocks
#define B_BF     42
#define B_WC0    43     // 97 blocks: Wc1/Wc2/Wgs (96) + BCONST (1)
#define B_ZAGG0  140    // 150
#define B_RAB0   290    // 150
#define B_HEAD0  440    // 361
#define B_FIN0   801    // 150
#define NBLKS    951
#define C1_TGT   43
#define C2_TGT   247    // 150 zagg + 97 wc/bconst
#define C3_TGT   150
#define C4_TGT   361

// ---- workspace float offsets (16B aligned) ----
#define OFF_CNT    0       // 16  (4 int counters + pad)        [zeroed]
#define OFF_SUMZ   16      // 128                                [zeroed]
#define OFF_SUMZ2  144     // 128                                [zeroed]
#define OFF_R1SUM  272     // 128                                [zeroed]
#define OFF_RACC   400     // 256                                [zeroed]
#define ZERO_BYTES (656 * 4)
#define OFF_U      656     // 1200
#define OFF_BCONST 1856    // 256
#define OFF_BF     2112    // 128
#define OFF_SUMA   2240    // 368 (361 used)
#define OFF_CSR    2608    // ints: rs[601] @ +0, src[9600] @ +604 (10208)
#define OFF_WF     12816   // 16384
#define OFF_WC1    29200   // 32768
#define OFF_WC2    61968   // 32768
#define OFF_WGS    94736   // 32768
#define OFF_Z      127504  // 76800
#define OFF_A      204304  // 153600
#define OFF_B      357904  // 153600

typedef _Float16 h2 __attribute__((ext_vector_type(2)));
typedef _Float16 h4 __attribute__((ext_vector_type(4)));
typedef _Float16 h8 __attribute__((ext_vector_type(8)));

__device__ __forceinline__ float dot2acc(h2 a, h2 b, float c) {
#if __has_builtin(__builtin_amdgcn_fdot2)
  return __builtin_amdgcn_fdot2(a, b, c, false);
#else
  return c + (float)a.x * (float)b.x + (float)a.y * (float)b.y;
#endif
}

__device__ __forceinline__ h2 relu2(h2 x) {
  h2 z = {(_Float16)0, (_Float16)0};
#if __has_builtin(__builtin_elementwise_max)
  return __builtin_elementwise_max(x, z);
#else
  h2 r;
  r.x = x.x > z.x ? x.x : z.x;
  r.y = x.y > z.y ? x.y : z.y;
  return r;
#endif
}

__device__ __forceinline__ h4 toh4(float4 v) {
  h4 r;
  r.x = (_Float16)v.x; r.y = (_Float16)v.y;
  r.z = (_Float16)v.z; r.w = (_Float16)v.w;
  return r;
}

struct KP {
  const float* feat; const int* ei;
  const float *g0W0, *g0ga, *g0be, *g0W1, *g0b1;
  const float *g1W0, *g1ga, *g1be, *g1W1, *g1b1;
  const float *aW0, *ab0, *aW1;
  const float *cW0, *cb0, *cW1, *cb1;
  float* ws; float* out;
};

// ---- producer/consumer gates (device-scope; co-residency guaranteed) ----
__device__ __forceinline__ void gate(int* c, int target) {
  if (threadIdx.x == 0) {
    int it = 0;
    while (__hip_atomic_load(c, __ATOMIC_RELAXED, __HIP_MEMORY_SCOPE_AGENT) < target) {
      __builtin_amdgcn_s_sleep(1);
      if (++it > (1 << 26)) break;   // failsafe: no infinite hang
    }
  }
  __syncthreads();
  __threadfence();   // acquire: drop stale L1/L2 lines before reading
}
__device__ __forceinline__ void arrive(int* c) {
  __syncthreads();   // all block threads done (vmcnt drained)
  __threadfence();   // release: write back dirty lines
  if (threadIdx.x == 0)
    __hip_atomic_fetch_add(c, 1, __ATOMIC_RELEASE, __HIP_MEMORY_SCOPE_AGENT);
}

__global__ __launch_bounds__(256, 4) void mega(KP p) {
  __shared__ float smem[9216];   // 36 KB union; 4 blocks/CU -> all 951 resident
  const int b = blockIdx.x, t = threadIdx.x;
  int* cnt = (int*)(p.ws + OFF_CNT);

  if (b < B_CSR) {
    // ---- u slice via dst-range filter scan ----
    float* us = smem;   // 48
    if (t < 48) us[t] = 0.f;
    __syncthreads();
    const int lo = b * 24, hi = lo + 24;
    for (int e = t; e < N_EDGES; e += 256) {
      int d = p.ei[N_EDGES + e];
      if (d >= lo && d < hi) {
        int s = p.ei[e];
        atomicAdd(&us[2 * (d - lo)],     p.feat[2 * s]);
        atomicAdd(&us[2 * (d - lo) + 1], p.feat[2 * s + 1]);
      }
    }
    __syncthreads();
    if (t < 48) p.ws[OFF_U + b * 48 + t] = us[t] + p.feat[b * 48 + t];
    arrive(&cnt[0]);
  } else if (b == B_CSR) {
    // ---- CSR by dst: cnt[600], bs[256], off[601] in LDS ----
    int* si = (int*)smem;
    int* cn = si; int* bs = si + 600; int* off = si + 856;
    int* rs_g = (int*)(p.ws + OFF_CSR);
    int* src_g = rs_g + 604;
    for (int i = t; i < 600; i += 256) cn[i] = 0;
    __syncthreads();
    for (int e = t; e < N_EDGES; e += 256) atomicAdd(&cn[p.ei[N_EDGES + e]], 1);
    __syncthreads();
    int lsum = 0;
    if (t < 200) lsum = cn[3 * t] + cn[3 * t + 1] + cn[3 * t + 2];
    bs[t] = lsum; __syncthreads();
    for (int d = 1; d < 256; d <<= 1) {
      int v = (t >= d) ? bs[t - d] : 0;
      __syncthreads();
      bs[t] += v;
      __syncthreads();
    }
    if (t < 200) {
      int base = bs[t] - lsum;
      off[3 * t] = base;
      off[3 * t + 1] = base + cn[3 * t];
      off[3 * t + 2] = base + cn[3 * t] + cn[3 * t + 1];
    }
    if (t == 0) off[600] = N_EDGES;
    __syncthreads();
    for (int i = t; i < 601; i += 256) rs_g[i] = off[i];
    for (int i = t; i < 600; i += 256) cn[i] = off[i];
    __syncthreads();
    for (int e = t; e < N_EDGES; e += 256) {
      int d = p.ei[N_EDGES + e];
      int pos = atomicAdd(&cn[d], 1);
      src_g[pos] = p.ei[e];
    }
    arrive(&cnt[0]);
  } else if (b < B_BF) {
    // ---- Wf = g0W1 @ g1W0 ----
    int o = (b - B_WF0) * 1024 + t * 4;
    int j = o >> 7, c = o & 127;
    float4 acc = make_float4(0, 0, 0, 0);
#pragma unroll 8
    for (int m = 0; m < HDIM; m++) {
      float w = p.g0W1[j * HDIM + m];
      const float4 v = *(const float4*)(p.g1W0 + m * HDIM + c);
      acc.x += w * v.x; acc.y += w * v.y; acc.z += w * v.z; acc.w += w * v.w;
    }
    *(float4*)(p.ws + OFF_WF + j * HDIM + c) = acc;
    arrive(&cnt[0]);
  } else if (b == B_BF) {
    // ---- BF = g0b1 @ g1W0 ----
    if (t < 128) {
      float a2 = 0.f;
#pragma unroll 8
      for (int m = 0; m < HDIM; m++) a2 += p.g0b1[m] * p.g1W0[m * HDIM + t];
      p.ws[OFF_BF + t] = a2;
    }
    arrive(&cnt[0]);
  } else if (b < B_ZAGG0) {
    // ---- Wc1/Wc2/Wgs (96) + BCONST (1) ----
    int idx = b - B_WC0;
    if (idx < 96) {
      int o = idx * 1024 + t * 4;
      int mat = o >> 15, rem = o & 32767;
      int j = rem >> 8, k = rem & 255;
      int rowbase = (mat == 0) ? HDIM : (mat == 1 ? 2 * HDIM : 0);
      const float* aw = p.aW0 + rowbase * HA + k;
      float4 acc = make_float4(0, 0, 0, 0);
#pragma unroll 8
      for (int m = 0; m < HDIM; m++) {
        float w = p.g1W1[j * HDIM + m];
        const float4 v = *(const float4*)(aw + m * HA);
        acc.x += w * v.x; acc.y += w * v.y; acc.z += w * v.z; acc.w += w * v.w;
      }
      int dst = (mat == 0) ? OFF_WC1 : (mat == 1 ? OFF_WC2 : OFF_WGS);
      *(float4*)(p.ws + dst + j * HA + k) = acc;
    } else {
      float acc = 0.f;
#pragma unroll 8
      for (int m = 0; m < HDIM; m++) {
        float gb = p.g1b1[m];
        acc += gb * (p.aW0[m * HA + t] + p.aW0[(HDIM + m) * HA + t] +
                     p.aW0[(2 * HDIM + m) * HA + t]);
      }
      p.ws[OFF_BCONST + t] = p.ab0[t] + acc;
    }
    arrive(&cnt[1]);
  } else if (b < B_RAB0) {
    // ---- zagg: z = r0agg@Wf + (1+deg)bf; channel stats ----
    gate(&cnt[0], C1_TGT);
    float2* u2   = (float2*)smem;       // 600
    float* bn    = smem + 1200;         // 384
    float* r0agg = smem + 1584;         // 512
    float* red   = smem + 2096;         // 256
    float* wred  = smem + 2352;         // 24
    const int n0 = (b - B_ZAGG0) * 4;
    const float2* ug = (const float2*)(p.ws + OFF_U);
    for (int i = t; i < 600; i += 256) u2[i] = ug[i];
    __syncthreads();
    float s0 = 0, s1 = 0, s00 = 0, s11 = 0, s01 = 0;
    for (int n = t; n < N_NODES; n += 256) {
      float u0 = u2[n].x, u1 = u2[n].y;
      s0 += u0; s1 += u1; s00 += u0 * u0; s11 += u1 * u1; s01 += u0 * u1;
    }
#pragma unroll
    for (int off = 32; off > 0; off >>= 1) {
      s0  += __shfl_xor(s0, off);  s1  += __shfl_xor(s1, off);
      s00 += __shfl_xor(s00, off); s11 += __shfl_xor(s11, off);
      s01 += __shfl_xor(s01, off);
    }
    const int wv = t >> 6, ln = t & 63;
    if (ln == 0) {
      wred[wv * 5 + 0] = s0;  wred[wv * 5 + 1] = s1;  wred[wv * 5 + 2] = s00;
      wred[wv * 5 + 3] = s11; wred[wv * 5 + 4] = s01;
    }
    __syncthreads();
    if (t < HDIM) {
      float tot[5];
#pragma unroll
      for (int q = 0; q < 5; q++)
        tot[q] = wred[q] + wred[5 + q] + wred[10 + q] + wred[15 + q];
      float m0 = tot[0] / 600.f, m1 = tot[1] / 600.f;
      float v00 = tot[2] / 600.f - m0 * m0;
      float v11 = tot[3] / 600.f - m1 * m1;
      float v01 = tot[4] / 600.f - m0 * m1;
      float W00 = p.g0W0[t], W01 = p.g0W0[HDIM + t];
      float var = W00 * W00 * v00 + W01 * W01 * v11 + 2.f * W00 * W01 * v01;
      float sc = p.g0ga[t] * rsqrtf(var + BN_EPS);
      float mu = m0 * W00 + m1 * W01;   // g0_b0 cancels in BN
      bn[t] = sc * W00; bn[128 + t] = sc * W01; bn[256 + t] = p.g0be[t] - mu * sc;
    }
    __syncthreads();
    const int* rs = (const int*)(p.ws + OFF_CSR);
    const int* srcv = rs + 604;
#pragma unroll
    for (int pq = 0; pq < 2; pq++) {
      int idx = pq * 256 + t, n = idx >> 7, c = idx & 127, node = n0 + n;
      float b0c = bn[c], b1c = bn[128 + c], b2c = bn[256 + c];
      float2 uo = u2[node];
      float acc = fmaxf(uo.x * b0c + uo.y * b1c + b2c, 0.f);
      int e0 = rs[node], e1 = rs[node + 1];
      for (int e = e0; e < e1; e++) {
        float2 us = u2[srcv[e]];
        acc += fmaxf(us.x * b0c + us.y * b1c + b2c, 0.f);
      }
      r0agg[n * 128 + c] = acc;
    }
    __syncthreads();
    const float* Wf = p.ws + OFF_WF;
    const float* bf = p.ws + OFF_BF;
    float zs = 0.f, zs2 = 0.f;
#pragma unroll
    for (int pq = 0; pq < 2; pq++) {
      int idx = pq * 256 + t, n = idx >> 7, c = idx & 127, node = n0 + n;
      const float* row = r0agg + n * 128;
      int deg = rs[node + 1] - rs[node];
      float acc = (1.f + (float)deg) * bf[c];
#pragma unroll 8
      for (int j = 0; j < HDIM; j++) acc += row[j] * Wf[j * HDIM + c];
      p.ws[OFF_Z + node * HDIM + c] = acc;
      zs += acc; zs2 += acc * acc;
    }
    red[t] = zs; __syncthreads();
    if (t < 128) atomicAdd(&p.ws[OFF_SUMZ + t], red[t] + red[t + 128]);
    __syncthreads();
    red[t] = zs2; __syncthreads();
    if (t < 128) atomicAdd(&p.ws[OFF_SUMZ2 + t], red[t] + red[t + 128]);
    arrive(&cnt[1]);
  } else if (b < B_HEAD0) {
    // ---- rab: r1 = BN-relu(z); A,B; R1SUM; RACC ----
    gate(&cnt[1], C2_TGT);
    float* r1    = smem;        // 512
    float* scl   = smem + 512;  // 128
    float* shf   = smem + 640;  // 128
    float* rsum4 = smem + 768;  // 128
    const int n0 = (b - B_RAB0) * 4;
    if (t < 128) {
      float mu = p.ws[OFF_SUMZ + t] * (1.f / 600.f);
      float var = p.ws[OFF_SUMZ2 + t] * (1.f / 600.f) - mu * mu;
      float sc = p.g1ga[t] * rsqrtf(var + BN_EPS);
      scl[t] = sc; shf[t] = p.g1be[t] - mu * sc;
    }
    __syncthreads();
#pragma unroll
    for (int pq = 0; pq < 2; pq++) {
      int idx = pq * 256 + t, n = idx >> 7, j = idx & 127;
      float z = p.ws[OFF_Z + (n0 + n) * HDIM + j];
      r1[n * 128 + j] = fmaxf(z * scl[j] + shf[j], 0.f);
    }
    __syncthreads();
    if (t < 128) {
      float s = r1[t] + r1[128 + t] + r1[256 + t] + r1[384 + t];
      rsum4[t] = s;
      atomicAdd(&p.ws[OFF_R1SUM + t], s);
    }
    __syncthreads();
    const float* wc1 = p.ws + OFF_WC1;
    const float* wc2 = p.ws + OFF_WC2;
    const float* wgs = p.ws + OFF_WGS;
    float a0 = 0, a1 = 0, a2 = 0, a3 = 0, b0 = 0, b1 = 0, b2 = 0, b3 = 0, rc = 0;
#pragma unroll 4
    for (int j = 0; j < HDIM; j++) {
      float w1 = wc1[j * HA + t], w2 = wc2[j * HA + t], wg = wgs[j * HA + t];
      float r0v = r1[j], r1v = r1[128 + j], r2v = r1[256 + j], r3v = r1[384 + j];
      a0 += r0v * w1; a1 += r1v * w1; a2 += r2v * w1; a3 += r3v * w1;
      b0 += r0v * w2; b1 += r1v * w2; b2 += r2v * w2; b3 += r3v * w2;
      rc += rsum4[j] * wg;
    }
    atomicAdd(&p.ws[OFF_RACC + t], rc);
    float* A = p.ws + OFF_A; float* Bm = p.ws + OFF_B;
    A[n0 * HA + t] = a0; A[(n0 + 1) * HA + t] = a1;
    A[(n0 + 2) * HA + t] = a2; A[(n0 + 3) * HA + t] = a3;
    Bm[n0 * HA + t] = b0; Bm[(n0 + 1) * HA + t] = b1;
    Bm[(n0 + 2) * HA + t] = b2; Bm[(n0 + 3) * HA + t] = b3;
    arrive(&cnt[2]);
  } else if (b < B_FIN0) {
    // ---- heads: fp16-dot2 logits + exp + tile sum; value on first block ----
    gate(&cnt[2], C3_TGT);
    h4* AsL    = (h4*)smem;              // 2048 (16 KB)
    h4* BsL    = (h4*)(smem + 4096);     // 2048 (16 KB)
    h4* wlp    = (h4*)(smem + 8192);     // 64
    h4* hsp    = (h4*)(smem + 8320);     // 64
    float* hsl = smem + 8448;            // 256
    float* ge  = smem + 8704;            // 128
    float* geh = smem + 8832;            // 128
    float* red = smem + 8960;            // 256
    const int hb = b - B_HEAD0;

    hsl[t] = p.ws[OFF_RACC + t] * (1.f / 600.f) + p.ws[OFF_BCONST + t];

    if (hb == 0) {     // value head (fp32)
      if (t < 128) ge[t] = p.ws[OFF_R1SUM + t] * (1.f / 600.f);
      __syncthreads();
      if (t < 128) {
        float a0 = p.g1b1[t], a1 = 0.f, a2 = 0.f, a3 = 0.f;
#pragma unroll 4
        for (int j = 0; j < HDIM; j += 4) {
          a0 += ge[j]     * p.g1W1[(j)     * HDIM + t];
          a1 += ge[j + 1] * p.g1W1[(j + 1) * HDIM + t];
          a2 += ge[j + 2] * p.g1W1[(j + 2) * HDIM + t];
          a3 += ge[j + 3] * p.g1W1[(j + 3) * HDIM + t];
        }
        geh[t] = (a0 + a1) + (a2 + a3);
      }
      __syncthreads();
      {
        float v0 = p.cb0[t], v1 = 0.f, v2 = 0.f, v3 = 0.f;
#pragma unroll 4
        for (int c = 0; c < HDIM; c += 4) {
          v0 += geh[c]     * p.cW0[(c)     * HC + t];
          v1 += geh[c + 1] * p.cW0[(c + 1) * HC + t];
          v2 += geh[c + 2] * p.cW0[(c + 2) * HC + t];
          v3 += geh[c + 3] * p.cW0[(c + 3) * HC + t];
        }
        float v = fmaxf((v0 + v1) + (v2 + v3), 0.f);
        red[t] = v * p.cW1[t];
      }
      __syncthreads();
      for (int off = 128; off > 0; off >>= 1) {
        if (t < off) red[t] += red[t + off];
        __syncthreads();
      }
      if (t == 0) p.out[NN] = red[0] + p.cb1[0];
    }
    __syncthreads();
    if (t < 64) {
      wlp[t] = toh4(*(const float4*)(p.aW1 + 4 * t));
      hsp[t] = toh4(*(const float4*)(hsl + 4 * t));
    }
    __syncthreads();

    const int tj = hb % 19, ti = hb / 19;
    const int j0 = tj * 32, i0 = ti * 32;
    const float* A  = p.ws + OFF_A;
    const float* Bm = p.ws + OFF_B;
#pragma unroll
    for (int q = 0; q < 8; q++) {
      int f = q * 256 + t;
      int r = f >> 6, c4 = f & 63, k = c4 * 4;
      int sw = c4 * 32 + (r ^ (c4 & 30));
      float4 av = (j0 + r < N_NODES) ? *(const float4*)(A + (j0 + r) * HA + k)
                                     : make_float4(0, 0, 0, 0);
      AsL[sw] = toh4(av) + hsp[c4];
      float4 bv = (i0 + r < N_NODES) ? *(const float4*)(Bm + (i0 + r) * HA + k)
                                     : make_float4(0, 0, 0, 0);
      BsL[sw] = toh4(bv);
    }
    __syncthreads();

    const int tx = t & 15, ty = t >> 4;
    const int jl = tx * 2, il = ty * 2;
    float a00 = 0, a01 = 0, a10 = 0, a11 = 0;
#pragma unroll 8
    for (int kk2 = 0; kk2 < 64; kk2++) {
      int s = kk2 & 30;
      h8 va = *(h8*)&AsL[kk2 * 32 + (jl ^ s)];
      h8 vb = *(h8*)&BsL[kk2 * 32 + (il ^ s)];
      h4 vw = wlp[kk2];
      h2 wlo = __builtin_shufflevector(vw, vw, 0, 1);
      h2 whi = __builtin_shufflevector(vw, vw, 2, 3);
      h2 aj0lo = __builtin_shufflevector(va, va, 0, 1);
      h2 aj0hi = __builtin_shufflevector(va, va, 2, 3);
      h2 aj1lo = __builtin_shufflevector(va, va, 4, 5);
      h2 aj1hi = __builtin_shufflevector(va, va, 6, 7);
      h2 bi0lo = __builtin_shufflevector(vb, vb, 0, 1);
      h2 bi0hi = __builtin_shufflevector(vb, vb, 2, 3);
      h2 bi1lo = __builtin_shufflevector(vb, vb, 4, 5);
      h2 bi1hi = __builtin_shufflevector(vb, vb, 6, 7);
      a00 = dot2acc(relu2(aj0lo + bi0lo), wlo, a00);
      a00 = dot2acc(relu2(aj0hi + bi0hi), whi, a00);
      a01 = dot2acc(relu2(aj1lo + bi0lo), wlo, a01);
      a01 = dot2acc(relu2(aj1hi + bi0hi), whi, a01);
      a10 = dot2acc(relu2(aj0lo + bi1lo), wlo, a10);
      a10 = dot2acc(relu2(aj0hi + bi1hi), whi, a10);
      a11 = dot2acc(relu2(aj1lo + bi1lo), wlo, a11);
      a11 = dot2acc(relu2(aj1hi + bi1hi), whi, a11);
    }

    const int gi = i0 + il, gj = j0 + jl;
    const bool vi0 = gi < N_NODES, vi1 = gi + 1 < N_NODES;
    const bool vj0 = gj < N_NODES, vj1 = gj + 1 < N_NODES;
    float s = 0.f;
    if (vi0 && vj0) { float e = __expf(a00); p.out[gi * N_NODES + gj] = e; s += e; }
    if (vi0 && vj1) { float e = __expf(a01); p.out[gi * N_NODES + gj + 1] = e; s += e; }
    if (vi1 && vj0) { float e = __expf(a10); p.out[(gi + 1) * N_NODES + gj] = e; s += e; }
    if (vi1 && vj1) { float e = __expf(a11); p.out[(gi + 1) * N_NODES + gj + 1] = e; s += e; }
    __syncthreads();
    red[t] = s;
    __syncthreads();
    for (int off = 128; off > 0; off >>= 1) {
      if (t < off) red[t] += red[t + off];
      __syncthreads();
    }
    if (t == 0) p.ws[OFF_SUMA + hb] = red[0];
    arrive(&cnt[3]);
  } else {
    // ---- fin: global sum + scale (4 rows per block) ----
    gate(&cnt[3], C4_TGT);
    float* red = smem;
    const int fb = b - B_FIN0;
    const float* suma = p.ws + OFF_SUMA;
    float s = (t < NTILE ? suma[t] : 0.f) + (t + 256 < NTILE ? suma[t + 256] : 0.f);
    red[t] = s;
    __syncthreads();
    for (int off = 128; off > 0; off >>= 1) {
      if (t < off) red[t] += red[t + off];
      __syncthreads();
    }
    const float inv = 1.0f / red[0];
#pragma unroll
    for (int pass = 0; pass < 3; pass++) {
      int f4 = pass * 256 + t;
      if (f4 < 600) {
        int r = f4 / 150, c4 = (f4 % 150) * 4;
        float* pp = p.out + (fb * 4 + r) * N_NODES + c4;
        float4 v = *(const float4*)pp;
        v.x *= inv; v.y *= inv; v.z *= inv; v.w *= inv;
        *(float4*)pp = v;
      }
    }
  }
}

extern "C" void kernel_launch(void* const* d_in, const int* in_sizes, int n_in,
                              void* d_out, int out_size, void* d_ws, size_t ws_size,
                              hipStream_t stream) {
  KP p;
  p.feat = (const float*)d_in[0];
  p.ei   = (const int*)  d_in[1];
  p.g0W0 = (const float*)d_in[2];
  // d_in[3] = g0_b0: cancels inside BN
  p.g0ga = (const float*)d_in[4];  p.g0be = (const float*)d_in[5];
  p.g0W1 = (const float*)d_in[6];  p.g0b1 = (const float*)d_in[7];
  p.g1W0 = (const float*)d_in[8];
  // d_in[9] = g1_b0: cancels inside BN
  p.g1ga = (const float*)d_in[10]; p.g1be = (const float*)d_in[11];
  p.g1W1 = (const float*)d_in[12]; p.g1b1 = (const float*)d_in[13];
  p.aW0  = (const float*)d_in[14]; p.ab0  = (const float*)d_in[15];
  p.aW1  = (const float*)d_in[16];
  // d_in[17] = a_b1: uniform logit shift, cancels in softmax
  p.cW0  = (const float*)d_in[18]; p.cb0  = (const float*)d_in[19];
  p.cW1  = (const float*)d_in[20]; p.cb1  = (const float*)d_in[21];
  p.ws   = (float*)d_ws;
  p.out  = (float*)d_out;

  // zero counters + global accumulators (replay-safe)
  hipMemsetAsync(p.ws, 0, ZERO_BYTES, stream);
  mega<<<NBLKS, 256, 0, stream>>>(p);
}

// Round 12
// 86.547 us; speedup vs baseline: 3.0413x; 3.0413x over previous
//
#include <hip/hip_runtime.h>
#include <math.h>

#define N_NODES 600
#define N_EDGES 9600
#define HDIM    128
#define HA      256
#define HC      256
#define NN      360000
#define BN_EPS  1e-5f
#define NTILE   247    // 13 (i, 48 rows) x 19 (j, 32 cols)

// ---- workspace float offsets (16B aligned) ----
#define OFF_U      0       // 1200
#define OFF_BN0    1200    // 384   w0'[128] w1'[128] b'[128]
#define OFF_BCONST 1584    // 256
#define OFF_BF     1840    // 128
#define OFF_SUMZ   1968    // 128   (zeroed K1)
#define OFF_SUMZ2  2096    // 128   (zeroed K1)
#define OFF_R1SUM  2224    // 128   (zeroed K1)
#define OFF_RACC   2352    // 256   (zeroed K1)
#define OFF_SUMA   2608    // 256 (247 used)
#define OFF_CSR    2864    // ints: rs[601] @ +0, src[9600] @ +604 (10208)
#define OFF_WF     13072   // 16384
#define OFF_WC1    29456   // 32768
#define OFF_WC2    62224   // 32768
#define OFF_WGS    94992   // 32768
#define OFF_Z      127760  // 76800
#define OFF_A      204560  // 153600
#define OFF_B      358160  // 153600

typedef _Float16 h2 __attribute__((ext_vector_type(2)));
typedef _Float16 h4 __attribute__((ext_vector_type(4)));
typedef _Float16 h8 __attribute__((ext_vector_type(8)));

__device__ __forceinline__ float dot2acc(h2 a, h2 b, float c) {
#if __has_builtin(__builtin_amdgcn_fdot2)
  return __builtin_amdgcn_fdot2(a, b, c, false);
#else
  return c + (float)a.x * (float)b.x + (float)a.y * (float)b.y;
#endif
}

__device__ __forceinline__ h2 relu2(h2 x) {
  h2 z = {(_Float16)0, (_Float16)0};
#if __has_builtin(__builtin_elementwise_max)
  return __builtin_elementwise_max(x, z);
#else
  h2 r;
  r.x = x.x > z.x ? x.x : z.x;
  r.y = x.y > z.y ? x.y : z.y;
  return r;
#endif
}

__device__ __forceinline__ h4 toh4(float4 v) {
  h4 r;
  r.x = (_Float16)v.x; r.y = (_Float16)v.y;
  r.z = (_Float16)v.z; r.w = (_Float16)v.w;
  return r;
}

struct KP {
  const float* feat; const int* ei;
  const float *g0W0, *g0ga, *g0be, *g0W1, *g0b1;
  const float *g1W0, *g1ga, *g1be, *g1W1, *g1b1;
  const float *aW0, *ab0, *aW1;
  const float *cW0, *cb0, *cW1, *cb1;
  float* ws; float* out;
};

// =================== K1: prep (44 blocks) ===================
// b 0..24 : u slice via dst-range filter scan
// b 25    : CSR by dst
// b 26    : BN0 affine (redundant LDS scatter + 2x2 moments, one block)
// b 27..42: Wf = g0W1 @ g1W0
// b 43    : BF + zero accumulators
__global__ __launch_bounds__(256) void k_indep(KP p) {
  __shared__ float sm[1536];   // CSR uses si[0..1456]; BN0 uses 1200+24
  const int b = blockIdx.x, t = threadIdx.x;

  if (b < 25) {
    float* us = sm;   // 48
    if (t < 48) us[t] = 0.f;
    __syncthreads();
    const int lo = b * 24, hi = lo + 24;
    for (int e = t; e < N_EDGES; e += 256) {
      int d = p.ei[N_EDGES + e];
      if (d >= lo && d < hi) {
        int s = p.ei[e];
        atomicAdd(&us[2 * (d - lo)],     p.feat[2 * s]);
        atomicAdd(&us[2 * (d - lo) + 1], p.feat[2 * s + 1]);
      }
    }
    __syncthreads();
    if (t < 48) p.ws[OFF_U + b * 48 + t] = us[t] + p.feat[b * 48 + t];
  } else if (b == 25) {
    int* si = (int*)sm;
    int* cn = si; int* bs = si + 600; int* off = si + 856;
    int* rs_g = (int*)(p.ws + OFF_CSR);
    int* src_g = rs_g + 604;
    for (int i = t; i < 600; i += 256) cn[i] = 0;
    __syncthreads();
    for (int e = t; e < N_EDGES; e += 256) atomicAdd(&cn[p.ei[N_EDGES + e]], 1);
    __syncthreads();
    int lsum = 0;
    if (t < 200) lsum = cn[3 * t] + cn[3 * t + 1] + cn[3 * t + 2];
    bs[t] = lsum; __syncthreads();
    for (int d = 1; d < 256; d <<= 1) {
      int v = (t >= d) ? bs[t - d] : 0;
      __syncthreads();
      bs[t] += v;
      __syncthreads();
    }
    if (t < 200) {
      int base = bs[t] - lsum;
      off[3 * t] = base;
      off[3 * t + 1] = base + cn[3 * t];
      off[3 * t + 2] = base + cn[3 * t] + cn[3 * t + 1];
    }
    if (t == 0) off[600] = N_EDGES;
    __syncthreads();
    for (int i = t; i < 601; i += 256) rs_g[i] = off[i];
    for (int i = t; i < 600; i += 256) cn[i] = off[i];
    __syncthreads();
    for (int e = t; e < N_EDGES; e += 256) {
      int d = p.ei[N_EDGES + e];
      int pos = atomicAdd(&cn[d], 1);
      src_g[pos] = p.ei[e];
    }
  } else if (b == 26) {
    // ---- BN0: own scatter -> u -> 2x2 moments -> affine params ----
    float* ua = sm;            // 1200
    float* wred = sm + 1200;   // 24
    for (int i = t; i < 1200; i += 256) ua[i] = 0.f;
    __syncthreads();
    for (int e = t; e < N_EDGES; e += 256) {
      int s = p.ei[e], d = p.ei[N_EDGES + e];
      atomicAdd(&ua[2 * d],     p.feat[2 * s]);
      atomicAdd(&ua[2 * d + 1], p.feat[2 * s + 1]);
    }
    __syncthreads();
    float s0 = 0, s1 = 0, s00 = 0, s11 = 0, s01 = 0;
    for (int n = t; n < N_NODES; n += 256) {
      float u0 = p.feat[2 * n] + ua[2 * n];
      float u1 = p.feat[2 * n + 1] + ua[2 * n + 1];
      s0 += u0; s1 += u1; s00 += u0 * u0; s11 += u1 * u1; s01 += u0 * u1;
    }
#pragma unroll
    for (int off = 32; off > 0; off >>= 1) {
      s0  += __shfl_xor(s0, off);  s1  += __shfl_xor(s1, off);
      s00 += __shfl_xor(s00, off); s11 += __shfl_xor(s11, off);
      s01 += __shfl_xor(s01, off);
    }
    const int wv = t >> 6, ln = t & 63;
    if (ln == 0) {
      wred[wv * 5 + 0] = s0;  wred[wv * 5 + 1] = s1;  wred[wv * 5 + 2] = s00;
      wred[wv * 5 + 3] = s11; wred[wv * 5 + 4] = s01;
    }
    __syncthreads();
    if (t < HDIM) {
      float tot[5];
#pragma unroll
      for (int q = 0; q < 5; q++)
        tot[q] = wred[q] + wred[5 + q] + wred[10 + q] + wred[15 + q];
      float m0 = tot[0] / 600.f, m1 = tot[1] / 600.f;
      float v00 = tot[2] / 600.f - m0 * m0;
      float v11 = tot[3] / 600.f - m1 * m1;
      float v01 = tot[4] / 600.f - m0 * m1;
      float W00 = p.g0W0[t], W01 = p.g0W0[HDIM + t];
      float var = W00 * W00 * v00 + W01 * W01 * v11 + 2.f * W00 * W01 * v01;
      float sc = p.g0ga[t] * rsqrtf(var + BN_EPS);
      float mu = m0 * W00 + m1 * W01;   // g0_b0 cancels in BN
      p.ws[OFF_BN0 + t] = sc * W00;
      p.ws[OFF_BN0 + 128 + t] = sc * W01;
      p.ws[OFF_BN0 + 256 + t] = p.g0be[t] - mu * sc;
    }
  } else if (b < 43) {   // 16 blocks: Wf
    int o = (b - 27) * 1024 + t * 4;
    int j = o >> 7, c = o & 127;
    float4 acc = make_float4(0, 0, 0, 0);
#pragma unroll 8
    for (int m = 0; m < HDIM; m++) {
      float w = p.g0W1[j * HDIM + m];
      const float4 v = *(const float4*)(p.g1W0 + m * HDIM + c);
      acc.x += w * v.x; acc.y += w * v.y; acc.z += w * v.z; acc.w += w * v.w;
    }
    *(float4*)(p.ws + OFF_WF + j * HDIM + c) = acc;
  } else {  // b == 43: BF + zeros
    p.ws[OFF_RACC + t] = 0.f;
    if (t < 128) {
      float a2 = 0.f;
#pragma unroll 8
      for (int m = 0; m < HDIM; m++) a2 += p.g0b1[m] * p.g1W0[m * HDIM + t];
      p.ws[OFF_BF + t] = a2;
      p.ws[OFF_SUMZ + t] = 0.f;
      p.ws[OFF_SUMZ2 + t] = 0.f;
      p.ws[OFF_R1SUM + t] = 0.f;
    }
  }
}

// =================== K2: z + stats (b<150); Wc1/Wc2/Wgs (150..245); BCONST ==
__global__ __launch_bounds__(256) void k_zagg(KP p) {
  __shared__ float2 u2[600];
  __shared__ float bn[384];
  __shared__ float r0agg[512];
  __shared__ float red[256];
  const int b = blockIdx.x, t = threadIdx.x;

  if (b >= 150) {
    if (b < 246) {     // Wc1/Wc2/Wgs = g1W1 @ {Wn1, Wn2, Ws}
      int o = (b - 150) * 1024 + t * 4;
      int mat = o >> 15, rem = o & 32767;
      int j = rem >> 8, k = rem & 255;
      int rowbase = (mat == 0) ? HDIM : (mat == 1 ? 2 * HDIM : 0);
      const float* aw = p.aW0 + rowbase * HA + k;
      float4 acc = make_float4(0, 0, 0, 0);
#pragma unroll 8
      for (int m = 0; m < HDIM; m++) {
        float w = p.g1W1[j * HDIM + m];
        const float4 v = *(const float4*)(aw + m * HA);
        acc.x += w * v.x; acc.y += w * v.y; acc.z += w * v.z; acc.w += w * v.w;
      }
      int dst = (mat == 0) ? OFF_WC1 : (mat == 1 ? OFF_WC2 : OFF_WGS);
      *(float4*)(p.ws + dst + j * HA + k) = acc;
    } else {           // b == 246: BCONST
      float acc = 0.f;
#pragma unroll 8
      for (int m = 0; m < HDIM; m++) {
        float gb = p.g1b1[m];
        acc += gb * (p.aW0[m * HA + t] + p.aW0[(HDIM + m) * HA + t] +
                     p.aW0[(2 * HDIM + m) * HA + t]);
      }
      p.ws[OFF_BCONST + t] = p.ab0[t] + acc;
    }
    return;
  }

  const int n0 = b * 4;
  const float2* ug = (const float2*)(p.ws + OFF_U);
  for (int i = t; i < 600; i += 256) u2[i] = ug[i];
  for (int i = t; i < 384; i += 256) bn[i] = p.ws[OFF_BN0 + i];
  __syncthreads();
  const int* rs = (const int*)(p.ws + OFF_CSR);
  const int* srcv = rs + 604;
#pragma unroll
  for (int pq = 0; pq < 2; pq++) {
    int idx = pq * 256 + t, n = idx >> 7, c = idx & 127, node = n0 + n;
    float b0c = bn[c], b1c = bn[128 + c], b2c = bn[256 + c];
    float2 uo = u2[node];
    float acc = fmaxf(uo.x * b0c + uo.y * b1c + b2c, 0.f);
    int e0 = rs[node], e1 = rs[node + 1];
    for (int e = e0; e < e1; e++) {
      float2 us = u2[srcv[e]];
      acc += fmaxf(us.x * b0c + us.y * b1c + b2c, 0.f);
    }
    r0agg[n * 128 + c] = acc;
  }
  __syncthreads();
  const float* Wf = p.ws + OFF_WF;
  const float* bf = p.ws + OFF_BF;
  float zs = 0.f, zs2 = 0.f;
#pragma unroll
  for (int pq = 0; pq < 2; pq++) {
    int idx = pq * 256 + t, n = idx >> 7, c = idx & 127, node = n0 + n;
    const float* row = r0agg + n * 128;
    int deg = rs[node + 1] - rs[node];
    float acc = (1.f + (float)deg) * bf[c];
#pragma unroll 8
    for (int j = 0; j < HDIM; j++) acc += row[j] * Wf[j * HDIM + c];
    p.ws[OFF_Z + node * HDIM + c] = acc;
    zs += acc; zs2 += acc * acc;
  }
  red[t] = zs; __syncthreads();
  if (t < 128) atomicAdd(&p.ws[OFF_SUMZ + t], red[t] + red[t + 128]);
  __syncthreads();
  red[t] = zs2; __syncthreads();
  if (t < 128) atomicAdd(&p.ws[OFF_SUMZ2 + t], red[t] + red[t + 128]);
}

// =================== K3: r1 = BN-relu(z); A,B; R1SUM; RACC ==================
__global__ __launch_bounds__(256) void k_rab(KP p) {
  __shared__ float r1[4 * 128];
  __shared__ float scl[128], shf[128], rsum4[128];
  const int b = blockIdx.x, t = threadIdx.x, n0 = b * 4;
  if (t < 128) {
    float mu = p.ws[OFF_SUMZ + t] * (1.f / 600.f);
    float var = p.ws[OFF_SUMZ2 + t] * (1.f / 600.f) - mu * mu;
    float sc = p.g1ga[t] * rsqrtf(var + BN_EPS);
    scl[t] = sc; shf[t] = p.g1be[t] - mu * sc;
  }
  __syncthreads();
#pragma unroll
  for (int pq = 0; pq < 2; pq++) {
    int idx = pq * 256 + t, n = idx >> 7, j = idx & 127;
    float z = p.ws[OFF_Z + (n0 + n) * HDIM + j];
    r1[n * 128 + j] = fmaxf(z * scl[j] + shf[j], 0.f);
  }
  __syncthreads();
  if (t < 128) {
    float s = r1[t] + r1[128 + t] + r1[256 + t] + r1[384 + t];
    rsum4[t] = s;
    atomicAdd(&p.ws[OFF_R1SUM + t], s);
  }
  __syncthreads();
  const float* wc1 = p.ws + OFF_WC1;
  const float* wc2 = p.ws + OFF_WC2;
  const float* wgs = p.ws + OFF_WGS;
  float a0 = 0, a1 = 0, a2 = 0, a3 = 0, b0 = 0, b1 = 0, b2 = 0, b3 = 0, rc = 0;
#pragma unroll 4
  for (int j = 0; j < HDIM; j++) {
    float w1 = wc1[j * HA + t], w2 = wc2[j * HA + t], wg = wgs[j * HA + t];
    float r0v = r1[j], r1v = r1[128 + j], r2v = r1[256 + j], r3v = r1[384 + j];
    a0 += r0v * w1; a1 += r1v * w1; a2 += r2v * w1; a3 += r3v * w1;
    b0 += r0v * w2; b1 += r1v * w2; b2 += r2v * w2; b3 += r3v * w2;
    rc += rsum4[j] * wg;
  }
  atomicAdd(&p.ws[OFF_RACC + t], rc);
  float* A = p.ws + OFF_A; float* Bm = p.ws + OFF_B;
  A[n0 * HA + t] = a0; A[(n0 + 1) * HA + t] = a1;
  A[(n0 + 2) * HA + t] = a2; A[(n0 + 3) * HA + t] = a3;
  Bm[n0 * HA + t] = b0; Bm[(n0 + 1) * HA + t] = b1;
  Bm[(n0 + 2) * HA + t] = b2; Bm[(n0 + 3) * HA + t] = b3;
}

// =================== K4: fp16-dot2 logits 48x32 tile; exp; value on b0 ======
__global__ __launch_bounds__(256) void k_heads(KP p) {
  __shared__ h4 AsL[2048];     // [c4(64)][col(32)]  A-tile (j), swz s=c4&14
  __shared__ h4 BsL[3072];     // [c4(64)][row(48)]  B-tile (i), swz s=c4&14
  __shared__ h4 wlp[64];
  __shared__ h4 hsp[64];
  __shared__ float hsl[256];
  __shared__ float ge[128];
  __shared__ float geh[128];
  __shared__ float red[256];
  const int b = blockIdx.x, t = threadIdx.x;

  hsl[t] = p.ws[OFF_RACC + t] * (1.f / 600.f) + p.ws[OFF_BCONST + t];

  if (b == 0) {     // value head (fp32)
    if (t < 128) ge[t] = p.ws[OFF_R1SUM + t] * (1.f / 600.f);
    __syncthreads();
    if (t < 128) {
      float a0 = p.g1b1[t], a1 = 0.f, a2 = 0.f, a3 = 0.f;
#pragma unroll 4
      for (int j = 0; j < HDIM; j += 4) {
        a0 += ge[j]     * p.g1W1[(j)     * HDIM + t];
        a1 += ge[j + 1] * p.g1W1[(j + 1) * HDIM + t];
        a2 += ge[j + 2] * p.g1W1[(j + 2) * HDIM + t];
        a3 += ge[j + 3] * p.g1W1[(j + 3) * HDIM + t];
      }
      geh[t] = (a0 + a1) + (a2 + a3);
    }
    __syncthreads();
    {
      float v0 = p.cb0[t], v1 = 0.f, v2 = 0.f, v3 = 0.f;
#pragma unroll 4
      for (int c = 0; c < HDIM; c += 4) {
        v0 += geh[c]     * p.cW0[(c)     * HC + t];
        v1 += geh[c + 1] * p.cW0[(c + 1) * HC + t];
        v2 += geh[c + 2] * p.cW0[(c + 2) * HC + t];
        v3 += geh[c + 3] * p.cW0[(c + 3) * HC + t];
      }
      float v = fmaxf((v0 + v1) + (v2 + v3), 0.f);
      red[t] = v * p.cW1[t];
    }
    __syncthreads();
    for (int off = 128; off > 0; off >>= 1) {
      if (t < off) red[t] += red[t + off];
      __syncthreads();
    }
    if (t == 0) p.out[NN] = red[0] + p.cb1[0];
  }
  __syncthreads();
  if (t < 64) {
    wlp[t] = toh4(*(const float4*)(p.aW1 + 4 * t));
    hsp[t] = toh4(*(const float4*)(hsl + 4 * t));
  }
  __syncthreads();

  // ---- stage A (32 rows, +hs) and B (48 rows) as packed fp16, k-major ----
  const int ti = b / 19, tj = b % 19;
  const int i0 = ti * 48, j0 = tj * 32;
  const float* A  = p.ws + OFF_A;
  const float* Bm = p.ws + OFF_B;
#pragma unroll
  for (int q = 0; q < 8; q++) {         // A: 2048 slots
    int f = q * 256 + t;
    int r = f >> 6, c4 = f & 63, k = c4 * 4;
    float4 av = (j0 + r < N_NODES) ? *(const float4*)(A + (j0 + r) * HA + k)
                                   : make_float4(0, 0, 0, 0);
    AsL[c4 * 32 + (r ^ (c4 & 14))] = toh4(av) + hsp[c4];
  }
#pragma unroll
  for (int q = 0; q < 12; q++) {        // B: 3072 slots
    int f = q * 256 + t;
    int r = f >> 6, c4 = f & 63, k = c4 * 4;
    float4 bv = (i0 + r < N_NODES) ? *(const float4*)(Bm + (i0 + r) * HA + k)
                                   : make_float4(0, 0, 0, 0);
    BsL[c4 * 48 + (r ^ (c4 & 14))] = toh4(bv);
  }
  __syncthreads();

  // ---- main loop: 64 k-quads; A h8 (2 cols) + 3x B h4 (rows) + dot2 ----
  const int tx = t & 15, ty = t >> 4;
  const int jl = tx * 2, il = ty * 3;
  float a00 = 0, a01 = 0, a10 = 0, a11 = 0, a20 = 0, a21 = 0;  // a{i}{j}
#pragma unroll 8
  for (int kk2 = 0; kk2 < 64; kk2++) {
    int s = kk2 & 14;
    h8 va = *(h8*)&AsL[kk2 * 32 + (jl ^ s)];
    h4 vb0 = BsL[kk2 * 48 + ((il)     ^ s)];
    h4 vb1 = BsL[kk2 * 48 + ((il + 1) ^ s)];
    h4 vb2 = BsL[kk2 * 48 + ((il + 2) ^ s)];
    h4 vw = wlp[kk2];
    h2 wlo = __builtin_shufflevector(vw, vw, 0, 1);
    h2 whi = __builtin_shufflevector(vw, vw, 2, 3);
    h2 aj0lo = __builtin_shufflevector(va, va, 0, 1);
    h2 aj0hi = __builtin_shufflevector(va, va, 2, 3);
    h2 aj1lo = __builtin_shufflevector(va, va, 4, 5);
    h2 aj1hi = __builtin_shufflevector(va, va, 6, 7);
    h2 b0lo = __builtin_shufflevector(vb0, vb0, 0, 1);
    h2 b0hi = __builtin_shufflevector(vb0, vb0, 2, 3);
    h2 b1lo = __builtin_shufflevector(vb1, vb1, 0, 1);
    h2 b1hi = __builtin_shufflevector(vb1, vb1, 2, 3);
    h2 b2lo = __builtin_shufflevector(vb2, vb2, 0, 1);
    h2 b2hi = __builtin_shufflevector(vb2, vb2, 2, 3);
    a00 = dot2acc(relu2(aj0lo + b0lo), wlo, a00);
    a00 = dot2acc(relu2(aj0hi + b0hi), whi, a00);
    a01 = dot2acc(relu2(aj1lo + b0lo), wlo, a01);
    a01 = dot2acc(relu2(aj1hi + b0hi), whi, a01);
    a10 = dot2acc(relu2(aj0lo + b1lo), wlo, a10);
    a10 = dot2acc(relu2(aj0hi + b1hi), whi, a10);
    a11 = dot2acc(relu2(aj1lo + b1lo), wlo, a11);
    a11 = dot2acc(relu2(aj1hi + b1hi), whi, a11);
    a20 = dot2acc(relu2(aj0lo + b2lo), wlo, a20);
    a20 = dot2acc(relu2(aj0hi + b2hi), whi, a20);
    a21 = dot2acc(relu2(aj1lo + b2lo), wlo, a21);
    a21 = dot2acc(relu2(aj1hi + b2hi), whi, a21);
  }

  // ---- epilogue: exp (logits bounded), tile sum ----
  const int gi = i0 + il, gj = j0 + jl;
  const bool vi0 = gi < N_NODES, vi1 = gi + 1 < N_NODES, vi2 = gi + 2 < N_NODES;
  const bool vj0 = gj < N_NODES, vj1 = gj + 1 < N_NODES;
  float s = 0.f;
  if (vj0) {
    if (vi0) { float e = __expf(a00); p.out[(gi)     * N_NODES + gj] = e; s += e; }
    if (vi1) { float e = __expf(a10); p.out[(gi + 1) * N_NODES + gj] = e; s += e; }
    if (vi2) { float e = __expf(a20); p.out[(gi + 2) * N_NODES + gj] = e; s += e; }
  }
  if (vj1) {
    if (vi0) { float e = __expf(a01); p.out[(gi)     * N_NODES + gj + 1] = e; s += e; }
    if (vi1) { float e = __expf(a11); p.out[(gi + 1) * N_NODES + gj + 1] = e; s += e; }
    if (vi2) { float e = __expf(a21); p.out[(gi + 2) * N_NODES + gj + 1] = e; s += e; }
  }
  __syncthreads();
  red[t] = s;
  __syncthreads();
  for (int off = 128; off > 0; off >>= 1) {
    if (t < off) red[t] += red[t + off];
    __syncthreads();
  }
  if (t == 0) p.ws[OFF_SUMA + b] = red[0];
}

// =================== K5: global sum + scale (150 blocks x 4 rows) ===========
__global__ __launch_bounds__(256) void k_fin(KP p) {
  __shared__ float red[256];
  const int b = blockIdx.x, t = threadIdx.x;
  const float* suma = p.ws + OFF_SUMA;
  red[t] = (t < NTILE) ? suma[t] : 0.f;
  __syncthreads();
  for (int off = 128; off > 0; off >>= 1) {
    if (t < off) red[t] += red[t + off];
    __syncthreads();
  }
  const float inv = 1.0f / red[0];
#pragma unroll
  for (int pass = 0; pass < 3; pass++) {
    int f4 = pass * 256 + t;
    if (f4 < 600) {
      int r = f4 / 150, c4 = (f4 % 150) * 4;
      float* pp = p.out + (b * 4 + r) * N_NODES + c4;
      float4 v = *(const float4*)pp;
      v.x *= inv; v.y *= inv; v.z *= inv; v.w *= inv;
      *(float4*)pp = v;
    }
  }
}

extern "C" void kernel_launch(void* const* d_in, const int* in_sizes, int n_in,
                              void* d_out, int out_size, void* d_ws, size_t ws_size,
                              hipStream_t stream) {
  KP p;
  p.feat = (const float*)d_in[0];
  p.ei   = (const int*)  d_in[1];
  p.g0W0 = (const float*)d_in[2];
  // d_in[3] = g0_b0: cancels inside BN
  p.g0ga = (const float*)d_in[4];  p.g0be = (const float*)d_in[5];
  p.g0W1 = (const float*)d_in[6];  p.g0b1 = (const float*)d_in[7];
  p.g1W0 = (const float*)d_in[8];
  // d_in[9] = g1_b0: cancels inside BN
  p.g1ga = (const float*)d_in[10]; p.g1be = (const float*)d_in[11];
  p.g1W1 = (const float*)d_in[12]; p.g1b1 = (const float*)d_in[13];
  p.aW0  = (const float*)d_in[14]; p.ab0  = (const float*)d_in[15];
  p.aW1  = (const float*)d_in[16];
  // d_in[17] = a_b1: uniform logit shift, cancels in softmax
  p.cW0  = (const float*)d_in[18]; p.cb0  = (const float*)d_in[19];
  p.cW1  = (const float*)d_in[20]; p.cb1  = (const float*)d_in[21];
  p.ws   = (float*)d_ws;
  p.out  = (float*)d_out;

  k_indep<<<44,    256, 0, stream>>>(p);
  k_zagg <<<247,   256, 0, stream>>>(p);
  k_rab  <<<150,   256, 0, stream>>>(p);
  k_heads<<<NTILE, 256, 0, stream>>>(p);
  k_fin  <<<150,   256, 0, stream>>>(p);
}

// Round 13
// 85.092 us; speedup vs baseline: 3.0933x; 1.0171x over previous
//
#include <hip/hip_runtime.h>
#include <math.h>

#define N_NODES 600
#define N_EDGES 9600
#define HDIM    128
#define HA      256
#define HC      256
#define NN      360000
#define BN_EPS  1e-5f
#define NTILE   361    // 19 x 19 logits tiles (32x32)

// ---- workspace float offsets (16B aligned) ----
#define OFF_U      0       // 1200   u = x + agg0
#define OFF_BCONST 1200    // 256    ab0 + g1b1@(Ws+Wn1+Wn2)
#define OFF_BF     1456    // 128    g0b1 @ g1W0
#define OFF_SUMZ   1584    // 128    z channel sums    (zeroed K1)
#define OFF_SUMZ2  1712    // 128    z channel sumsq   (zeroed K1)
#define OFF_R1SUM  1840    // 128    col sums of r1    (zeroed K1)
#define OFF_RACC   1968    // 256    (sum_n r1[n])@Wgs (zeroed K1)
#define OFF_BN0    2224    // 384    w0'[128] w1'[128] b'[128]
#define OFF_SUMA   2736    // 512    per-tile expsum
#define OFF_CSR    3248    // ints: rs[601] @ +0, src[9600] @ +604
#define OFF_WF     13456   // 16384  g0W1 @ g1W0
#define OFF_WC1    29840   // 32768  g1W1 @ Wn1
#define OFF_WC2    62608   // 32768  g1W1 @ Wn2
#define OFF_WGS    95376   // 32768  g1W1 @ Ws
#define OFF_Z      128144  // 76800
#define OFF_A      204944  // 153600
#define OFF_B      358544  // 153600

typedef _Float16 h2 __attribute__((ext_vector_type(2)));
typedef _Float16 h4 __attribute__((ext_vector_type(4)));
typedef _Float16 h8 __attribute__((ext_vector_type(8)));

__device__ __forceinline__ float dot2acc(h2 a, h2 b, float c) {
#if __has_builtin(__builtin_amdgcn_fdot2)
  return __builtin_amdgcn_fdot2(a, b, c, false);
#else
  return c + (float)a.x * (float)b.x + (float)a.y * (float)b.y;
#endif
}

__device__ __forceinline__ h2 relu2(h2 x) {
  h2 z = {(_Float16)0, (_Float16)0};
#if __has_builtin(__builtin_elementwise_max)
  return __builtin_elementwise_max(x, z);
#else
  h2 r;
  r.x = x.x > z.x ? x.x : z.x;
  r.y = x.y > z.y ? x.y : z.y;
  return r;
#endif
}

__device__ __forceinline__ h4 toh4(float4 v) {
  h4 r;
  r.x = (_Float16)v.x; r.y = (_Float16)v.y;
  r.z = (_Float16)v.z; r.w = (_Float16)v.w;
  return r;
}

struct KP {
  const float* feat; const int* ei;
  const float *g0W0, *g0ga, *g0be, *g0W1, *g0b1;
  const float *g1W0, *g1ga, *g1be, *g1W1, *g1b1;
  const float *aW0, *ab0, *aW1;
  const float *cW0, *cb0, *cW1, *cb1;
  float* ws; float* out;
};

// =================== K1: prep (44 blocks) ===================
// b 0..24 : u slice via dst-range filter scan
// b 25    : CSR by dst
// b 26    : BN0 affine (own LDS scatter + 2x2 moments, one block)
// b 27..42: Wf = g0W1 @ g1W0
// b 43    : BF + zero accumulators
__global__ __launch_bounds__(256) void k_indep(KP p) {
  __shared__ float sm[1536];   // CSR uses si[0..1456]; BN0 uses 1200+24
  const int b = blockIdx.x, t = threadIdx.x;

  if (b < 25) {
    float* us = sm;   // 48
    if (t < 48) us[t] = 0.f;
    __syncthreads();
    const int lo = b * 24, hi = lo + 24;
    for (int e = t; e < N_EDGES; e += 256) {
      int d = p.ei[N_EDGES + e];
      if (d >= lo && d < hi) {
        int s = p.ei[e];
        atomicAdd(&us[2 * (d - lo)],     p.feat[2 * s]);
        atomicAdd(&us[2 * (d - lo) + 1], p.feat[2 * s + 1]);
      }
    }
    __syncthreads();
    if (t < 48) p.ws[OFF_U + b * 48 + t] = us[t] + p.feat[b * 48 + t];
  } else if (b == 25) {
    int* si = (int*)sm;
    int* cn = si; int* bs = si + 600; int* off = si + 856;
    int* rs_g = (int*)(p.ws + OFF_CSR);
    int* src_g = rs_g + 604;
    for (int i = t; i < 600; i += 256) cn[i] = 0;
    __syncthreads();
    for (int e = t; e < N_EDGES; e += 256) atomicAdd(&cn[p.ei[N_EDGES + e]], 1);
    __syncthreads();
    int lsum = 0;
    if (t < 200) lsum = cn[3 * t] + cn[3 * t + 1] + cn[3 * t + 2];
    bs[t] = lsum; __syncthreads();
    for (int d = 1; d < 256; d <<= 1) {
      int v = (t >= d) ? bs[t - d] : 0;
      __syncthreads();
      bs[t] += v;
      __syncthreads();
    }
    if (t < 200) {
      int base = bs[t] - lsum;
      off[3 * t] = base;
      off[3 * t + 1] = base + cn[3 * t];
      off[3 * t + 2] = base + cn[3 * t] + cn[3 * t + 1];
    }
    if (t == 0) off[600] = N_EDGES;
    __syncthreads();
    for (int i = t; i < 601; i += 256) rs_g[i] = off[i];
    for (int i = t; i < 600; i += 256) cn[i] = off[i];
    __syncthreads();
    for (int e = t; e < N_EDGES; e += 256) {
      int d = p.ei[N_EDGES + e];
      int pos = atomicAdd(&cn[d], 1);
      src_g[pos] = p.ei[e];
    }
  } else if (b == 26) {
    // ---- BN0: own scatter -> u -> 2x2 moments -> affine params ----
    float* ua = sm;            // 1200
    float* wred = sm + 1200;   // 24
    for (int i = t; i < 1200; i += 256) ua[i] = 0.f;
    __syncthreads();
    for (int e = t; e < N_EDGES; e += 256) {
      int s = p.ei[e], d = p.ei[N_EDGES + e];
      atomicAdd(&ua[2 * d],     p.feat[2 * s]);
      atomicAdd(&ua[2 * d + 1], p.feat[2 * s + 1]);
    }
    __syncthreads();
    float s0 = 0, s1 = 0, s00 = 0, s11 = 0, s01 = 0;
    for (int n = t; n < N_NODES; n += 256) {
      float u0 = p.feat[2 * n] + ua[2 * n];
      float u1 = p.feat[2 * n + 1] + ua[2 * n + 1];
      s0 += u0; s1 += u1; s00 += u0 * u0; s11 += u1 * u1; s01 += u0 * u1;
    }
#pragma unroll
    for (int off = 32; off > 0; off >>= 1) {
      s0  += __shfl_xor(s0, off);  s1  += __shfl_xor(s1, off);
      s00 += __shfl_xor(s00, off); s11 += __shfl_xor(s11, off);
      s01 += __shfl_xor(s01, off);
    }
    const int wv = t >> 6, ln = t & 63;
    if (ln == 0) {
      wred[wv * 5 + 0] = s0;  wred[wv * 5 + 1] = s1;  wred[wv * 5 + 2] = s00;
      wred[wv * 5 + 3] = s11; wred[wv * 5 + 4] = s01;
    }
    __syncthreads();
    if (t < HDIM) {
      float tot[5];
#pragma unroll
      for (int q = 0; q < 5; q++)
        tot[q] = wred[q] + wred[5 + q] + wred[10 + q] + wred[15 + q];
      float m0 = tot[0] / 600.f, m1 = tot[1] / 600.f;
      float v00 = tot[2] / 600.f - m0 * m0;
      float v11 = tot[3] / 600.f - m1 * m1;
      float v01 = tot[4] / 600.f - m0 * m1;
      float W00 = p.g0W0[t], W01 = p.g0W0[HDIM + t];
      float var = W00 * W00 * v00 + W01 * W01 * v11 + 2.f * W00 * W01 * v01;
      float sc = p.g0ga[t] * rsqrtf(var + BN_EPS);
      float mu = m0 * W00 + m1 * W01;   // g0_b0 cancels in BN
      p.ws[OFF_BN0 + t] = sc * W00;
      p.ws[OFF_BN0 + 128 + t] = sc * W01;
      p.ws[OFF_BN0 + 256 + t] = p.g0be[t] - mu * sc;
    }
  } else if (b < 43) {   // 16 blocks: Wf
    int o = (b - 27) * 1024 + t * 4;
    int j = o >> 7, c = o & 127;
    float4 acc = make_float4(0, 0, 0, 0);
#pragma unroll 8
    for (int m = 0; m < HDIM; m++) {
      float w = p.g0W1[j * HDIM + m];
      const float4 v = *(const float4*)(p.g1W0 + m * HDIM + c);
      acc.x += w * v.x; acc.y += w * v.y; acc.z += w * v.z; acc.w += w * v.w;
    }
    *(float4*)(p.ws + OFF_WF + j * HDIM + c) = acc;
  } else {  // b == 43: BF + zeros
    p.ws[OFF_RACC + t] = 0.f;
    if (t < 128) {
      float a2 = 0.f;
#pragma unroll 8
      for (int m = 0; m < HDIM; m++) a2 += p.g0b1[m] * p.g1W0[m * HDIM + t];
      p.ws[OFF_BF + t] = a2;
      p.ws[OFF_SUMZ + t] = 0.f;
      p.ws[OFF_SUMZ2 + t] = 0.f;
      p.ws[OFF_R1SUM + t] = 0.f;
    }
  }
}

// =================== K2: z + stats (b<150); Wc1/Wc2/Wgs (150..245); BCONST ==
__global__ __launch_bounds__(256) void k_zagg(KP p) {
  __shared__ float2 u2[600];
  __shared__ float bn[384];
  __shared__ float r0agg[512];
  __shared__ float red[256];
  const int b = blockIdx.x, t = threadIdx.x;

  if (b >= 150) {
    if (b < 246) {     // Wc1/Wc2/Wgs = g1W1 @ {Wn1, Wn2, Ws}
      int o = (b - 150) * 1024 + t * 4;
      int mat = o >> 15, rem = o & 32767;
      int j = rem >> 8, k = rem & 255;
      int rowbase = (mat == 0) ? HDIM : (mat == 1 ? 2 * HDIM : 0);
      const float* aw = p.aW0 + rowbase * HA + k;
      float4 acc = make_float4(0, 0, 0, 0);
#pragma unroll 8
      for (int m = 0; m < HDIM; m++) {
        float w = p.g1W1[j * HDIM + m];
        const float4 v = *(const float4*)(aw + m * HA);
        acc.x += w * v.x; acc.y += w * v.y; acc.z += w * v.z; acc.w += w * v.w;
      }
      int dst = (mat == 0) ? OFF_WC1 : (mat == 1 ? OFF_WC2 : OFF_WGS);
      *(float4*)(p.ws + dst + j * HA + k) = acc;
    } else {           // b == 246: BCONST
      float acc = 0.f;
#pragma unroll 8
      for (int m = 0; m < HDIM; m++) {
        float gb = p.g1b1[m];
        acc += gb * (p.aW0[m * HA + t] + p.aW0[(HDIM + m) * HA + t] +
                     p.aW0[(2 * HDIM + m) * HA + t]);
      }
      p.ws[OFF_BCONST + t] = p.ab0[t] + acc;
    }
    return;
  }

  const int n0 = b * 4;
  const float2* ug = (const float2*)(p.ws + OFF_U);
  for (int i = t; i < 600; i += 256) u2[i] = ug[i];
  for (int i = t; i < 384; i += 256) bn[i] = p.ws[OFF_BN0 + i];
  __syncthreads();
  const int* rs = (const int*)(p.ws + OFF_CSR);
  const int* srcv = rs + 604;
#pragma unroll
  for (int pq = 0; pq < 2; pq++) {
    int idx = pq * 256 + t, n = idx >> 7, c = idx & 127, node = n0 + n;
    float b0c = bn[c], b1c = bn[128 + c], b2c = bn[256 + c];
    float2 uo = u2[node];
    float acc = fmaxf(uo.x * b0c + uo.y * b1c + b2c, 0.f);
    int e0 = rs[node], e1 = rs[node + 1];
    for (int e = e0; e < e1; e++) {
      float2 us = u2[srcv[e]];
      acc += fmaxf(us.x * b0c + us.y * b1c + b2c, 0.f);
    }
    r0agg[n * 128 + c] = acc;
  }
  __syncthreads();
  const float* Wf = p.ws + OFF_WF;
  const float* bf = p.ws + OFF_BF;
  float zs = 0.f, zs2 = 0.f;
#pragma unroll
  for (int pq = 0; pq < 2; pq++) {
    int idx = pq * 256 + t, n = idx >> 7, c = idx & 127, node = n0 + n;
    const float* row = r0agg + n * 128;
    int deg = rs[node + 1] - rs[node];
    float acc = (1.f + (float)deg) * bf[c];
#pragma unroll 8
    for (int j = 0; j < HDIM; j++) acc += row[j] * Wf[j * HDIM + c];
    p.ws[OFF_Z + node * HDIM + c] = acc;
    zs += acc; zs2 += acc * acc;
  }
  red[t] = zs; __syncthreads();
  if (t < 128) atomicAdd(&p.ws[OFF_SUMZ + t], red[t] + red[t + 128]);
  __syncthreads();
  red[t] = zs2; __syncthreads();
  if (t < 128) atomicAdd(&p.ws[OFF_SUMZ2 + t], red[t] + red[t + 128]);
}

// =================== K3: r1 = BN-relu(z); A,B; R1SUM; RACC ==================
__global__ __launch_bounds__(256) void k_rab(KP p) {
  __shared__ float r1[4 * 128];
  __shared__ float scl[128], shf[128], rsum4[128];
  const int b = blockIdx.x, t = threadIdx.x, n0 = b * 4;
  if (t < 128) {
    float mu = p.ws[OFF_SUMZ + t] * (1.f / 600.f);
    float var = p.ws[OFF_SUMZ2 + t] * (1.f / 600.f) - mu * mu;
    float sc = p.g1ga[t] * rsqrtf(var + BN_EPS);
    scl[t] = sc; shf[t] = p.g1be[t] - mu * sc;
  }
  __syncthreads();
#pragma unroll
  for (int pq = 0; pq < 2; pq++) {
    int idx = pq * 256 + t, n = idx >> 7, j = idx & 127;
    float z = p.ws[OFF_Z + (n0 + n) * HDIM + j];
    r1[n * 128 + j] = fmaxf(z * scl[j] + shf[j], 0.f);
  }
  __syncthreads();
  if (t < 128) {
    float s = r1[t] + r1[128 + t] + r1[256 + t] + r1[384 + t];
    rsum4[t] = s;
    atomicAdd(&p.ws[OFF_R1SUM + t], s);
  }
  __syncthreads();
  const float* wc1 = p.ws + OFF_WC1;
  const float* wc2 = p.ws + OFF_WC2;
  const float* wgs = p.ws + OFF_WGS;
  float a0 = 0, a1 = 0, a2 = 0, a3 = 0, b0 = 0, b1 = 0, b2 = 0, b3 = 0, rc = 0;
#pragma unroll 4
  for (int j = 0; j < HDIM; j++) {
    float w1 = wc1[j * HA + t], w2 = wc2[j * HA + t], wg = wgs[j * HA + t];
    float r0v = r1[j], r1v = r1[128 + j], r2v = r1[256 + j], r3v = r1[384 + j];
    a0 += r0v * w1; a1 += r1v * w1; a2 += r2v * w1; a3 += r3v * w1;
    b0 += r0v * w2; b1 += r1v * w2; b2 += r2v * w2; b3 += r3v * w2;
    rc += rsum4[j] * wg;
  }
  atomicAdd(&p.ws[OFF_RACC + t], rc);
  float* A = p.ws + OFF_A; float* Bm = p.ws + OFF_B;
  A[n0 * HA + t] = a0; A[(n0 + 1) * HA + t] = a1;
  A[(n0 + 2) * HA + t] = a2; A[(n0 + 3) * HA + t] = a3;
  Bm[n0 * HA + t] = b0; Bm[(n0 + 1) * HA + t] = b1;
  Bm[(n0 + 2) * HA + t] = b2; Bm[(n0 + 3) * HA + t] = b3;
}

// =================== K4: fp16-dot2 logits (32x32); exp (no max); value on b0 =
__global__ __launch_bounds__(256) void k_heads(KP p) {
  __shared__ h4 AsL[2048];     // [c4(64)][col(32)] swizzled, fp16
  __shared__ h4 BsL[2048];
  __shared__ h4 wlp[64];
  __shared__ h4 hsp[64];
  __shared__ float hsl[256];
  __shared__ float ge[128];
  __shared__ float geh[128];
  __shared__ float red[256];
  const int b = blockIdx.x, t = threadIdx.x;

  hsl[t] = p.ws[OFF_RACC + t] * (1.f / 600.f) + p.ws[OFF_BCONST + t];

  if (b == 0) {     // value head (fp32)
    if (t < 128) ge[t] = p.ws[OFF_R1SUM + t] * (1.f / 600.f);
    __syncthreads();
    if (t < 128) {
      float a0 = p.g1b1[t], a1 = 0.f, a2 = 0.f, a3 = 0.f;
#pragma unroll 4
      for (int j = 0; j < HDIM; j += 4) {
        a0 += ge[j]     * p.g1W1[(j)     * HDIM + t];
        a1 += ge[j + 1] * p.g1W1[(j + 1) * HDIM + t];
        a2 += ge[j + 2] * p.g1W1[(j + 2) * HDIM + t];
        a3 += ge[j + 3] * p.g1W1[(j + 3) * HDIM + t];
      }
      geh[t] = (a0 + a1) + (a2 + a3);
    }
    __syncthreads();
    {
      float v0 = p.cb0[t], v1 = 0.f, v2 = 0.f, v3 = 0.f;
#pragma unroll 4
      for (int c = 0; c < HDIM; c += 4) {
        v0 += geh[c]     * p.cW0[(c)     * HC + t];
        v1 += geh[c + 1] * p.cW0[(c + 1) * HC + t];
        v2 += geh[c + 2] * p.cW0[(c + 2) * HC + t];
        v3 += geh[c + 3] * p.cW0[(c + 3) * HC + t];
      }
      float v = fmaxf((v0 + v1) + (v2 + v3), 0.f);
      red[t] = v * p.cW1[t];
    }
    __syncthreads();
    for (int off = 128; off > 0; off >>= 1) {
      if (t < off) red[t] += red[t + off];
      __syncthreads();
    }
    if (t == 0) p.out[NN] = red[0] + p.cb1[0];
  }
  __syncthreads();
  if (t < 64) {
    wlp[t] = toh4(*(const float4*)(p.aW1 + 4 * t));
    hsp[t] = toh4(*(const float4*)(hsl + 4 * t));
  }
  __syncthreads();

  // ---- stage A (+hs) and B tiles as packed fp16, k-major, XOR-swizzled ----
  const int tj = b % 19, ti = b / 19;
  const int j0 = tj * 32, i0 = ti * 32;
  const float* A  = p.ws + OFF_A;
  const float* Bm = p.ws + OFF_B;
#pragma unroll
  for (int q = 0; q < 8; q++) {
    int f = q * 256 + t;
    int r = f >> 6;            // row in tile 0..31
    int c4 = f & 63;           // k-quad 0..63
    int k = c4 * 4;
    int sw = c4 * 32 + (r ^ (c4 & 30));
    float4 av = (j0 + r < N_NODES) ? *(const float4*)(A + (j0 + r) * HA + k)
                                   : make_float4(0, 0, 0, 0);
    AsL[sw] = toh4(av) + hsp[c4];
    float4 bv = (i0 + r < N_NODES) ? *(const float4*)(Bm + (i0 + r) * HA + k)
                                   : make_float4(0, 0, 0, 0);
    BsL[sw] = toh4(bv);
  }
  __syncthreads();

  // ---- main loop: per k-quad, 2 b128 + 1 b64 LDS; pk_add/pk_max/dot2 ----
  const int tx = t & 15, ty = t >> 4;
  const int jl = tx * 2, il = ty * 2;
  float a00 = 0, a01 = 0, a10 = 0, a11 = 0;   // a{i}{j}
#pragma unroll 8
  for (int kk2 = 0; kk2 < 64; kk2++) {
    int s = kk2 & 30;
    h8 va = *(h8*)&AsL[kk2 * 32 + (jl ^ s)];
    h8 vb = *(h8*)&BsL[kk2 * 32 + (il ^ s)];
    h4 vw = wlp[kk2];
    h2 wlo = __builtin_shufflevector(vw, vw, 0, 1);
    h2 whi = __builtin_shufflevector(vw, vw, 2, 3);
    h2 aj0lo = __builtin_shufflevector(va, va, 0, 1);
    h2 aj0hi = __builtin_shufflevector(va, va, 2, 3);
    h2 aj1lo = __builtin_shufflevector(va, va, 4, 5);
    h2 aj1hi = __builtin_shufflevector(va, va, 6, 7);
    h2 bi0lo = __builtin_shufflevector(vb, vb, 0, 1);
    h2 bi0hi = __builtin_shufflevector(vb, vb, 2, 3);
    h2 bi1lo = __builtin_shufflevector(vb, vb, 4, 5);
    h2 bi1hi = __builtin_shufflevector(vb, vb, 6, 7);
    a00 = dot2acc(relu2(aj0lo + bi0lo), wlo, a00);
    a00 = dot2acc(relu2(aj0hi + bi0hi), whi, a00);
    a01 = dot2acc(relu2(aj1lo + bi0lo), wlo, a01);
    a01 = dot2acc(relu2(aj1hi + bi0hi), whi, a01);
    a10 = dot2acc(relu2(aj0lo + bi1lo), wlo, a10);
    a10 = dot2acc(relu2(aj0hi + bi1hi), whi, a10);
    a11 = dot2acc(relu2(aj1lo + bi1lo), wlo, a11);
    a11 = dot2acc(relu2(aj1hi + bi1hi), whi, a11);
  }

  // ---- epilogue: exp (no max shift; logits bounded), tile sum ----
  const int gi = i0 + il, gj = j0 + jl;
  const bool vi0 = gi < N_NODES, vi1 = gi + 1 < N_NODES;
  const bool vj0 = gj < N_NODES, vj1 = gj + 1 < N_NODES;
  float s = 0.f;
  if (vi0 && vj0) { float e = __expf(a00); p.out[gi * N_NODES + gj] = e; s += e; }
  if (vi0 && vj1) { float e = __expf(a01); p.out[gi * N_NODES + gj + 1] = e; s += e; }
  if (vi1 && vj0) { float e = __expf(a10); p.out[(gi + 1) * N_NODES + gj] = e; s += e; }
  if (vi1 && vj1) { float e = __expf(a11); p.out[(gi + 1) * N_NODES + gj + 1] = e; s += e; }
  __syncthreads();
  red[t] = s;
  __syncthreads();
  for (int off = 128; off > 0; off >>= 1) {
    if (t < off) red[t] += red[t + off];
    __syncthreads();
  }
  if (t == 0) p.ws[OFF_SUMA + b] = red[0];
}

// =================== K5: global sum + scale (150 blocks x 4 rows) ===========
__global__ __launch_bounds__(256) void k_fin(KP p) {
  __shared__ float red[256];
  const int b = blockIdx.x, t = threadIdx.x;
  const float* suma = p.ws + OFF_SUMA;
  float s = (t < NTILE ? suma[t] : 0.f) + (t + 256 < NTILE ? suma[t + 256] : 0.f);
  red[t] = s;
  __syncthreads();
  for (int off = 128; off > 0; off >>= 1) {
    if (t < off) red[t] += red[t + off];
    __syncthreads();
  }
  const float inv = 1.0f / red[0];
#pragma unroll
  for (int pass = 0; pass < 3; pass++) {
    int f4 = pass * 256 + t;
    if (f4 < 600) {
      int r = f4 / 150, c4 = (f4 % 150) * 4;
      float* pp = p.out + (b * 4 + r) * N_NODES + c4;
      float4 v = *(const float4*)pp;
      v.x *= inv; v.y *= inv; v.z *= inv; v.w *= inv;
      *(float4*)pp = v;
    }
  }
}

extern "C" void kernel_launch(void* const* d_in, const int* in_sizes, int n_in,
                              void* d_out, int out_size, void* d_ws, size_t ws_size,
                              hipStream_t stream) {
  KP p;
  p.feat = (const float*)d_in[0];
  p.ei   = (const int*)  d_in[1];
  p.g0W0 = (const float*)d_in[2];
  // d_in[3] = g0_b0: cancels inside BN
  p.g0ga = (const float*)d_in[4];  p.g0be = (const float*)d_in[5];
  p.g0W1 = (const float*)d_in[6];  p.g0b1 = (const float*)d_in[7];
  p.g1W0 = (const float*)d_in[8];
  // d_in[9] = g1_b0: cancels inside BN
  p.g1ga = (const float*)d_in[10]; p.g1be = (const float*)d_in[11];
  p.g1W1 = (const float*)d_in[12]; p.g1b1 = (const float*)d_in[13];
  p.aW0  = (const float*)d_in[14]; p.ab0  = (const float*)d_in[15];
  p.aW1  = (const float*)d_in[16];
  // d_in[17] = a_b1: uniform logit shift, cancels in softmax
  p.cW0  = (const float*)d_in[18]; p.cb0  = (const float*)d_in[19];
  p.cW1  = (const float*)d_in[20]; p.cb1  = (const float*)d_in[21];
  p.ws   = (float*)d_ws;
  p.out  = (float*)d_out;

  k_indep<<<44,    256, 0, stream>>>(p);
  k_zagg <<<247,   256, 0, stream>>>(p);
  k_rab  <<<150,   256, 0, stream>>>(p);
  k_heads<<<NTILE, 256, 0, stream>>>(p);
  k_fin  <<<150,   256, 0, stream>>>(p);
}

// Round 14
// 77.549 us; speedup vs baseline: 3.3942x; 1.0973x over previous
//
#include <hip/hip_runtime.h>
#include <math.h>

#define N_NODES 600
#define N_EDGES 9600
#define HDIM    128
#define HA      256
#define HC      256
#define NN      360000
#define BN_EPS  1e-5f
#define NTILE   361    // 19 x 19 logits tiles (32x32)

// ---- workspace float offsets (16B aligned) ----
#define OFF_U      0       // 1200   u = x + agg0
#define OFF_BCONST 1200    // 256    ab0 + g1b1@(Ws+Wn1+Wn2)
#define OFF_BF     1456    // 128    g0b1 @ g1W0
#define OFF_SUMZ   1584    // 128    z channel sums    (zeroed K1)
#define OFF_SUMZ2  1712    // 128    z channel sumsq   (zeroed K1)
#define OFF_R1SUM  1840    // 128    col sums of r1    (zeroed K1)
#define OFF_RACC   1968    // 256    (sum_n r1[n])@Wgs (zeroed K1)
#define OFF_SUMA   2736    // 512    per-tile expsum
#define OFF_CSR    3248    // ints: rs[601] @ +0, src[9600] @ +604
#define OFF_WF     13456   // 16384  g0W1 @ g1W0
#define OFF_WC1    29840   // 32768  g1W1 @ Wn1
#define OFF_WC2    62608   // 32768  g1W1 @ Wn2
#define OFF_WGS    95376   // 32768  g1W1 @ Ws
#define OFF_Z      128144  // 76800
#define OFF_A      204944  // 153600
#define OFF_B      358544  // 153600

typedef _Float16 h2 __attribute__((ext_vector_type(2)));
typedef _Float16 h4 __attribute__((ext_vector_type(4)));
typedef _Float16 h8 __attribute__((ext_vector_type(8)));

__device__ __forceinline__ float dot2acc(h2 a, h2 b, float c) {
#if __has_builtin(__builtin_amdgcn_fdot2)
  return __builtin_amdgcn_fdot2(a, b, c, false);
#else
  return c + (float)a.x * (float)b.x + (float)a.y * (float)b.y;
#endif
}

__device__ __forceinline__ h2 relu2(h2 x) {
  h2 z = {(_Float16)0, (_Float16)0};
#if __has_builtin(__builtin_elementwise_max)
  return __builtin_elementwise_max(x, z);
#else
  h2 r;
  r.x = x.x > z.x ? x.x : z.x;
  r.y = x.y > z.y ? x.y : z.y;
  return r;
#endif
}

__device__ __forceinline__ h4 toh4(float4 v) {
  h4 r;
  r.x = (_Float16)v.x; r.y = (_Float16)v.y;
  r.z = (_Float16)v.z; r.w = (_Float16)v.w;
  return r;
}

struct KP {
  const float* feat; const int* ei;
  const float *g0W0, *g0ga, *g0be, *g0W1, *g0b1;
  const float *g1W0, *g1ga, *g1be, *g1W1, *g1b1;
  const float *aW0, *ab0, *aW1;
  const float *cW0, *cb0, *cW1, *cb1;
  float* ws; float* out;
};

// =================== K1: prep (43 blocks) ===================
// b 0..24 : u slice via dst-range filter scan
// b 25    : CSR by dst
// b 26..41: Wf = g0W1 @ g1W0
// b 42    : BF + zero accumulators
__global__ __launch_bounds__(256) void k_indep(KP p) {
  __shared__ float sm[1536];   // CSR block uses si[0..1456]
  const int b = blockIdx.x, t = threadIdx.x;

  if (b < 25) {
    float* us = sm;   // 48
    if (t < 48) us[t] = 0.f;
    __syncthreads();
    const int lo = b * 24, hi = lo + 24;
    for (int e = t; e < N_EDGES; e += 256) {
      int d = p.ei[N_EDGES + e];
      if (d >= lo && d < hi) {
        int s = p.ei[e];
        atomicAdd(&us[2 * (d - lo)],     p.feat[2 * s]);
        atomicAdd(&us[2 * (d - lo) + 1], p.feat[2 * s + 1]);
      }
    }
    __syncthreads();
    if (t < 48) p.ws[OFF_U + b * 48 + t] = us[t] + p.feat[b * 48 + t];
  } else if (b == 25) {
    int* si = (int*)sm;
    int* cnt = si; int* bs = si + 600; int* off = si + 856;
    int* rs_g = (int*)(p.ws + OFF_CSR);
    int* src_g = rs_g + 604;
    for (int i = t; i < 600; i += 256) cnt[i] = 0;
    __syncthreads();
    for (int e = t; e < N_EDGES; e += 256) atomicAdd(&cnt[p.ei[N_EDGES + e]], 1);
    __syncthreads();
    int lsum = 0;
    if (t < 200) lsum = cnt[3 * t] + cnt[3 * t + 1] + cnt[3 * t + 2];
    bs[t] = lsum; __syncthreads();
    for (int d = 1; d < 256; d <<= 1) {
      int v = (t >= d) ? bs[t - d] : 0;
      __syncthreads();
      bs[t] += v;
      __syncthreads();
    }
    if (t < 200) {
      int base = bs[t] - lsum;
      off[3 * t] = base;
      off[3 * t + 1] = base + cnt[3 * t];
      off[3 * t + 2] = base + cnt[3 * t] + cnt[3 * t + 1];
    }
    if (t == 0) off[600] = N_EDGES;
    __syncthreads();
    for (int i = t; i < 601; i += 256) rs_g[i] = off[i];
    for (int i = t; i < 600; i += 256) cnt[i] = off[i];
    __syncthreads();
    for (int e = t; e < N_EDGES; e += 256) {
      int d = p.ei[N_EDGES + e];
      int pos = atomicAdd(&cnt[d], 1);
      src_g[pos] = p.ei[e];
    }
  } else if (b < 42) {   // 16 blocks: Wf
    int o = (b - 26) * 1024 + t * 4;
    int j = o >> 7, c = o & 127;
    float4 acc = make_float4(0, 0, 0, 0);
#pragma unroll 8
    for (int m = 0; m < HDIM; m++) {
      float w = p.g0W1[j * HDIM + m];
      const float4 v = *(const float4*)(p.g1W0 + m * HDIM + c);
      acc.x += w * v.x; acc.y += w * v.y; acc.z += w * v.z; acc.w += w * v.w;
    }
    *(float4*)(p.ws + OFF_WF + j * HDIM + c) = acc;
  } else {  // b == 42: BF + zeros
    p.ws[OFF_RACC + t] = 0.f;
    if (t < 128) {
      float a2 = 0.f;
#pragma unroll 8
      for (int m = 0; m < HDIM; m++) a2 += p.g0b1[m] * p.g1W0[m * HDIM + t];
      p.ws[OFF_BF + t] = a2;
      p.ws[OFF_SUMZ + t] = 0.f;
      p.ws[OFF_SUMZ2 + t] = 0.f;
      p.ws[OFF_R1SUM + t] = 0.f;
    }
  }
}

// =================== K2: z + stats (b<150); Wc1/Wc2/Wgs (150..245); BCONST ==
__global__ __launch_bounds__(256) void k_zagg(KP p) {
  __shared__ float2 u2[600];
  __shared__ float bn[384];
  __shared__ float r0agg[512];
  __shared__ float red[256];
  __shared__ float wred[24];
  const int b = blockIdx.x, t = threadIdx.x;

  if (b >= 150) {
    if (b < 246) {     // Wc1/Wc2/Wgs = g1W1 @ {Wn1, Wn2, Ws}
      int o = (b - 150) * 1024 + t * 4;
      int mat = o >> 15, rem = o & 32767;
      int j = rem >> 8, k = rem & 255;
      int rowbase = (mat == 0) ? HDIM : (mat == 1 ? 2 * HDIM : 0);
      const float* aw = p.aW0 + rowbase * HA + k;
      float4 acc = make_float4(0, 0, 0, 0);
#pragma unroll 8
      for (int m = 0; m < HDIM; m++) {
        float w = p.g1W1[j * HDIM + m];
        const float4 v = *(const float4*)(aw + m * HA);
        acc.x += w * v.x; acc.y += w * v.y; acc.z += w * v.z; acc.w += w * v.w;
      }
      int dst = (mat == 0) ? OFF_WC1 : (mat == 1 ? OFF_WC2 : OFF_WGS);
      *(float4*)(p.ws + dst + j * HA + k) = acc;
    } else {           // b == 246: BCONST
      float acc = 0.f;
#pragma unroll 8
      for (int m = 0; m < HDIM; m++) {
        float gb = p.g1b1[m];
        acc += gb * (p.aW0[m * HA + t] + p.aW0[(HDIM + m) * HA + t] +
                     p.aW0[(2 * HDIM + m) * HA + t]);
      }
      p.ws[OFF_BCONST + t] = p.ab0[t] + acc;
    }
    return;
  }

  const int n0 = b * 4;
  const float2* ug = (const float2*)(p.ws + OFF_U);
  for (int i = t; i < 600; i += 256) u2[i] = ug[i];
  __syncthreads();
  float s0 = 0, s1 = 0, s00 = 0, s11 = 0, s01 = 0;
  for (int n = t; n < N_NODES; n += 256) {
    float u0 = u2[n].x, u1 = u2[n].y;
    s0 += u0; s1 += u1; s00 += u0 * u0; s11 += u1 * u1; s01 += u0 * u1;
  }
#pragma unroll
  for (int off = 32; off > 0; off >>= 1) {
    s0  += __shfl_xor(s0, off);  s1  += __shfl_xor(s1, off);
    s00 += __shfl_xor(s00, off); s11 += __shfl_xor(s11, off);
    s01 += __shfl_xor(s01, off);
  }
  const int wv = t >> 6, ln = t & 63;
  if (ln == 0) {
    wred[wv * 5 + 0] = s0;  wred[wv * 5 + 1] = s1;  wred[wv * 5 + 2] = s00;
    wred[wv * 5 + 3] = s11; wred[wv * 5 + 4] = s01;
  }
  __syncthreads();
  if (t < HDIM) {
    float tot[5];
#pragma unroll
    for (int q = 0; q < 5; q++)
      tot[q] = wred[q] + wred[5 + q] + wred[10 + q] + wred[15 + q];
    float m0 = tot[0] / 600.f, m1 = tot[1] / 600.f;
    float v00 = tot[2] / 600.f - m0 * m0;
    float v11 = tot[3] / 600.f - m1 * m1;
    float v01 = tot[4] / 600.f - m0 * m1;
    float W00 = p.g0W0[t], W01 = p.g0W0[HDIM + t];
    float var = W00 * W00 * v00 + W01 * W01 * v11 + 2.f * W00 * W01 * v01;
    float sc = p.g0ga[t] * rsqrtf(var + BN_EPS);
    float mu = m0 * W00 + m1 * W01;   // g0_b0 cancels in BN
    bn[t] = sc * W00; bn[128 + t] = sc * W01; bn[256 + t] = p.g0be[t] - mu * sc;
  }
  __syncthreads();
  const int* rs = (const int*)(p.ws + OFF_CSR);
  const int* srcv = rs + 604;
#pragma unroll
  for (int pq = 0; pq < 2; pq++) {
    int idx = pq * 256 + t, n = idx >> 7, c = idx & 127, node = n0 + n;
    float b0c = bn[c], b1c = bn[128 + c], b2c = bn[256 + c];
    float2 uo = u2[node];
    float acc = fmaxf(uo.x * b0c + uo.y * b1c + b2c, 0.f);
    int e0 = rs[node], e1 = rs[node + 1];
    for (int e = e0; e < e1; e++) {
      float2 us = u2[srcv[e]];
      acc += fmaxf(us.x * b0c + us.y * b1c + b2c, 0.f);
    }
    r0agg[n * 128 + c] = acc;
  }
  __syncthreads();
  const float* Wf = p.ws + OFF_WF;
  const float* bf = p.ws + OFF_BF;
  float zs = 0.f, zs2 = 0.f;
#pragma unroll
  for (int pq = 0; pq < 2; pq++) {
    int idx = pq * 256 + t, n = idx >> 7, c = idx & 127, node = n0 + n;
    const float* row = r0agg + n * 128;
    int deg = rs[node + 1] - rs[node];
    float acc = (1.f + (float)deg) * bf[c];
#pragma unroll 8
    for (int j = 0; j < HDIM; j++) acc += row[j] * Wf[j * HDIM + c];
    p.ws[OFF_Z + node * HDIM + c] = acc;
    zs += acc; zs2 += acc * acc;
  }
  red[t] = zs; __syncthreads();
  if (t < 128) atomicAdd(&p.ws[OFF_SUMZ + t], red[t] + red[t + 128]);
  __syncthreads();
  red[t] = zs2; __syncthreads();
  if (t < 128) atomicAdd(&p.ws[OFF_SUMZ2 + t], red[t] + red[t + 128]);
}

// =================== K3: r1 = BN-relu(z); A,B; R1SUM; RACC ==================
__global__ __launch_bounds__(256) void k_rab(KP p) {
  __shared__ float r1[4 * 128];
  __shared__ float scl[128], shf[128], rsum4[128];
  const int b = blockIdx.x, t = threadIdx.x, n0 = b * 4;
  if (t < 128) {
    float mu = p.ws[OFF_SUMZ + t] * (1.f / 600.f);
    float var = p.ws[OFF_SUMZ2 + t] * (1.f / 600.f) - mu * mu;
    float sc = p.g1ga[t] * rsqrtf(var + BN_EPS);
    scl[t] = sc; shf[t] = p.g1be[t] - mu * sc;
  }
  __syncthreads();
#pragma unroll
  for (int pq = 0; pq < 2; pq++) {
    int idx = pq * 256 + t, n = idx >> 7, j = idx & 127;
    float z = p.ws[OFF_Z + (n0 + n) * HDIM + j];
    r1[n * 128 + j] = fmaxf(z * scl[j] + shf[j], 0.f);
  }
  __syncthreads();
  if (t < 128) {
    float s = r1[t] + r1[128 + t] + r1[256 + t] + r1[384 + t];
    rsum4[t] = s;
    atomicAdd(&p.ws[OFF_R1SUM + t], s);
  }
  __syncthreads();
  const float* wc1 = p.ws + OFF_WC1;
  const float* wc2 = p.ws + OFF_WC2;
  const float* wgs = p.ws + OFF_WGS;
  float a0 = 0, a1 = 0, a2 = 0, a3 = 0, b0 = 0, b1 = 0, b2 = 0, b3 = 0, rc = 0;
#pragma unroll 4
  for (int j = 0; j < HDIM; j++) {
    float w1 = wc1[j * HA + t], w2 = wc2[j * HA + t], wg = wgs[j * HA + t];
    float r0v = r1[j], r1v = r1[128 + j], r2v = r1[256 + j], r3v = r1[384 + j];
    a0 += r0v * w1; a1 += r1v * w1; a2 += r2v * w1; a3 += r3v * w1;
    b0 += r0v * w2; b1 += r1v * w2; b2 += r2v * w2; b3 += r3v * w2;
    rc += rsum4[j] * wg;
  }
  atomicAdd(&p.ws[OFF_RACC + t], rc);
  float* A = p.ws + OFF_A; float* Bm = p.ws + OFF_B;
  A[n0 * HA + t] = a0; A[(n0 + 1) * HA + t] = a1;
  A[(n0 + 2) * HA + t] = a2; A[(n0 + 3) * HA + t] = a3;
  Bm[n0 * HA + t] = b0; Bm[(n0 + 1) * HA + t] = b1;
  Bm[(n0 + 2) * HA + t] = b2; Bm[(n0 + 3) * HA + t] = b3;
}

// =================== K4: fp16-dot2 logits (32x32); exp (no max); value on b0 =
__global__ __launch_bounds__(256) void k_heads(KP p) {
  __shared__ h4 AsL[2048];     // [c4(64)][col(32)] swizzled, fp16
  __shared__ h4 BsL[2048];
  __shared__ h4 wlp[64];
  __shared__ h4 hsp[64];
  __shared__ float hsl[256];
  __shared__ float ge[128];
  __shared__ float geh[128];
  __shared__ float red[256];
  const int b = blockIdx.x, t = threadIdx.x;

  hsl[t] = p.ws[OFF_RACC + t] * (1.f / 600.f) + p.ws[OFF_BCONST + t];

  if (b == 0) {     // value head (fp32)
    if (t < 128) ge[t] = p.ws[OFF_R1SUM + t] * (1.f / 600.f);
    __syncthreads();
    if (t < 128) {
      float a0 = p.g1b1[t], a1 = 0.f, a2 = 0.f, a3 = 0.f;
#pragma unroll 4
      for (int j = 0; j < HDIM; j += 4) {
        a0 += ge[j]     * p.g1W1[(j)     * HDIM + t];
        a1 += ge[j + 1] * p.g1W1[(j + 1) * HDIM + t];
        a2 += ge[j + 2] * p.g1W1[(j + 2) * HDIM + t];
        a3 += ge[j + 3] * p.g1W1[(j + 3) * HDIM + t];
      }
      geh[t] = (a0 + a1) + (a2 + a3);
    }
    __syncthreads();
    {
      float v0 = p.cb0[t], v1 = 0.f, v2 = 0.f, v3 = 0.f;
#pragma unroll 4
      for (int c = 0; c < HDIM; c += 4) {
        v0 += geh[c]     * p.cW0[(c)     * HC + t];
        v1 += geh[c + 1] * p.cW0[(c + 1) * HC + t];
        v2 += geh[c + 2] * p.cW0[(c + 2) * HC + t];
        v3 += geh[c + 3] * p.cW0[(c + 3) * HC + t];
      }
      float v = fmaxf((v0 + v1) + (v2 + v3), 0.f);
      red[t] = v * p.cW1[t];
    }
    __syncthreads();
    for (int off = 128; off > 0; off >>= 1) {
      if (t < off) red[t] += red[t + off];
      __syncthreads();
    }
    if (t == 0) p.out[NN] = red[0] + p.cb1[0];
  }
  __syncthreads();
  if (t < 64) {
    wlp[t] = toh4(*(const float4*)(p.aW1 + 4 * t));
    hsp[t] = toh4(*(const float4*)(hsl + 4 * t));
  }
  __syncthreads();

  // ---- stage A (+hs) and B tiles as packed fp16, k-major, XOR-swizzled ----
  const int tj = b % 19, ti = b / 19;
  const int j0 = tj * 32, i0 = ti * 32;
  const float* A  = p.ws + OFF_A;
  const float* Bm = p.ws + OFF_B;
#pragma unroll
  for (int q = 0; q < 8; q++) {
    int f = q * 256 + t;
    int r = f >> 6;            // row in tile 0..31
    int c4 = f & 63;           // k-quad 0..63
    int k = c4 * 4;
    int sw = c4 * 32 + (r ^ (c4 & 30));
    float4 av = (j0 + r < N_NODES) ? *(const float4*)(A + (j0 + r) * HA + k)
                                   : make_float4(0, 0, 0, 0);
    AsL[sw] = toh4(av) + hsp[c4];
    float4 bv = (i0 + r < N_NODES) ? *(const float4*)(Bm + (i0 + r) * HA + k)
                                   : make_float4(0, 0, 0, 0);
    BsL[sw] = toh4(bv);
  }
  __syncthreads();

  // ---- main loop: per k-quad, 2 b128 + 1 b64 LDS; pk_add/pk_max/dot2 ----
  const int tx = t & 15, ty = t >> 4;
  const int jl = tx * 2, il = ty * 2;
  float a00 = 0, a01 = 0, a10 = 0, a11 = 0;   // a{i}{j}
#pragma unroll 8
  for (int kk2 = 0; kk2 < 64; kk2++) {
    int s = kk2 & 30;
    h8 va = *(h8*)&AsL[kk2 * 32 + (jl ^ s)];
    h8 vb = *(h8*)&BsL[kk2 * 32 + (il ^ s)];
    h4 vw = wlp[kk2];
    h2 wlo = __builtin_shufflevector(vw, vw, 0, 1);
    h2 whi = __builtin_shufflevector(vw, vw, 2, 3);
    h2 aj0lo = __builtin_shufflevector(va, va, 0, 1);
    h2 aj0hi = __builtin_shufflevector(va, va, 2, 3);
    h2 aj1lo = __builtin_shufflevector(va, va, 4, 5);
    h2 aj1hi = __builtin_shufflevector(va, va, 6, 7);
    h2 bi0lo = __builtin_shufflevector(vb, vb, 0, 1);
    h2 bi0hi = __builtin_shufflevector(vb, vb, 2, 3);
    h2 bi1lo = __builtin_shufflevector(vb, vb, 4, 5);
    h2 bi1hi = __builtin_shufflevector(vb, vb, 6, 7);
    a00 = dot2acc(relu2(aj0lo + bi0lo), wlo, a00);
    a00 = dot2acc(relu2(aj0hi + bi0hi), whi, a00);
    a01 = dot2acc(relu2(aj1lo + bi0lo), wlo, a01);
    a01 = dot2acc(relu2(aj1hi + bi0hi), whi, a01);
    a10 = dot2acc(relu2(aj0lo + bi1lo), wlo, a10);
    a10 = dot2acc(relu2(aj0hi + bi1hi), whi, a10);
    a11 = dot2acc(relu2(aj1lo + bi1lo), wlo, a11);
    a11 = dot2acc(relu2(aj1hi + bi1hi), whi, a11);
  }

  // ---- epilogue: exp (no max shift; logits bounded), tile sum ----
  const int gi = i0 + il, gj = j0 + jl;
  const bool vi0 = gi < N_NODES, vi1 = gi + 1 < N_NODES;
  const bool vj0 = gj < N_NODES, vj1 = gj + 1 < N_NODES;
  float s = 0.f;
  if (vi0 && vj0) { float e = __expf(a00); p.out[gi * N_NODES + gj] = e; s += e; }
  if (vi0 && vj1) { float e = __expf(a01); p.out[gi * N_NODES + gj + 1] = e; s += e; }
  if (vi1 && vj0) { float e = __expf(a10); p.out[(gi + 1) * N_NODES + gj] = e; s += e; }
  if (vi1 && vj1) { float e = __expf(a11); p.out[(gi + 1) * N_NODES + gj + 1] = e; s += e; }
  __syncthreads();
  red[t] = s;
  __syncthreads();
  for (int off = 128; off > 0; off >>= 1) {
    if (t < off) red[t] += red[t + off];
    __syncthreads();
  }
  if (t == 0) p.ws[OFF_SUMA + b] = red[0];
}

// =================== K5: global sum + scale (150 blocks x 4 rows) ===========
__global__ __launch_bounds__(256) void k_fin(KP p) {
  __shared__ float red[256];
  const int b = blockIdx.x, t = threadIdx.x;
  const float* suma = p.ws + OFF_SUMA;
  float s = (t < NTILE ? suma[t] : 0.f) + (t + 256 < NTILE ? suma[t + 256] : 0.f);
  red[t] = s;
  __syncthreads();
  for (int off = 128; off > 0; off >>= 1) {
    if (t < off) red[t] += red[t + off];
    __syncthreads();
  }
  const float inv = 1.0f / red[0];
#pragma unroll
  for (int pass = 0; pass < 3; pass++) {
    int f4 = pass * 256 + t;
    if (f4 < 600) {
      int r = f4 / 150, c4 = (f4 % 150) * 4;
      float* pp = p.out + (b * 4 + r) * N_NODES + c4;
      float4 v = *(const float4*)pp;
      v.x *= inv; v.y *= inv; v.z *= inv; v.w *= inv;
      *(float4*)pp = v;
    }
  }
}

extern "C" void kernel_launch(void* const* d_in, const int* in_sizes, int n_in,
                              void* d_out, int out_size, void* d_ws, size_t ws_size,
                              hipStream_t stream) {
  KP p;
  p.feat = (const float*)d_in[0];
  p.ei   = (const int*)  d_in[1];
  p.g0W0 = (const float*)d_in[2];
  // d_in[3] = g0_b0: cancels inside BN
  p.g0ga = (const float*)d_in[4];  p.g0be = (const float*)d_in[5];
  p.g0W1 = (const float*)d_in[6];  p.g0b1 = (const float*)d_in[7];
  p.g1W0 = (const float*)d_in[8];
  // d_in[9] = g1_b0: cancels inside BN
  p.g1ga = (const float*)d_in[10]; p.g1be = (const float*)d_in[11];
  p.g1W1 = (const float*)d_in[12]; p.g1b1 = (const float*)d_in[13];
  p.aW0  = (const float*)d_in[14]; p.ab0  = (const float*)d_in[15];
  p.aW1  = (const float*)d_in[16];
  // d_in[17] = a_b1: uniform logit shift, cancels in softmax
  p.cW0  = (const float*)d_in[18]; p.cb0  = (const float*)d_in[19];
  p.cW1  = (const float*)d_in[20]; p.cb1  = (const float*)d_in[21];
  p.ws   = (float*)d_ws;
  p.out  = (float*)d_out;

  k_indep<<<43,    256, 0, stream>>>(p);
  k_zagg <<<247,   256, 0, stream>>>(p);
  k_rab  <<<150,   256, 0, stream>>>(p);
  k_heads<<<NTILE, 256, 0, stream>>>(p);
  k_fin  <<<150,   256, 0, stream>>>(p);
}